// Round 12
// baseline (670.509 us; speedup 1.0000x reference)
//
#include <hip/hip_runtime.h>
#include <hip/hip_bf16.h>

#define DEVFN static __device__ __forceinline__

constexpr int NN = 16384;
constexpr int EE = 65536;
constexpr int GG = 512;
constexpr float AVG_LOG_F = 1.0227308671603782f; // (sum d*log d, d=1..4, hist 1,2,3,4)/10

typedef _Float16 hfrag __attribute__((ext_vector_type(8))); // 8 fp16 = 4 VGPR (MFMA A/B)
typedef __attribute__((ext_vector_type(4))) float f4;       // MFMA C/D
typedef __attribute__((ext_vector_type(8))) unsigned short us8v; // 16B fp16 vector

// fp32 <-> fp16 (RNE, native v_cvt). Measured (r5-r8): bf16 slabs +0.0097
// absmax; fp16 slabs noise-level. All intermediates + GEMM operands fp16.
DEVFN unsigned short f2h(float f) {
  _Float16 h = (_Float16)f;
  unsigned short r; __builtin_memcpy(&r, &h, 2); return r;
}
DEVFN float h2f(unsigned short s) {
  _Float16 h; __builtin_memcpy(&h, &s, 2); return (float)h;
}

// load 8 fp16 (single 16B) -> float[8]
DEVFN void ld8hf(const unsigned short* p, float* o) {
  us8v v = *(const us8v*)p;
#pragma unroll
  for (int i = 0; i < 8; ++i) o[i] = h2f(v[i]);
}

// XOR swizzle for packed fp16 [R][K] operand arrays staged with global_load_lds:
// element (row,k) lives at row*K + swk(row,k). Within each 32-wide K window the
// four 8-element slots are permuted by (row>>1)&3 so a wave's ds_read_b128
// fragment reads become a permutation of a contiguous 1 KB region ->
// bank-conflict-free. global_load_lds copies LINEARLY, so the swizzle is baked
// into the packed global layout (both-sides rule, #21). Fragment reads use the
// LOCAL tile row; staging bases must be 8-row aligned so (row>>1)&3 matches.
DEVFN int swk(int row, int k) {
  return (k & ~31) + ((((k >> 3) & 3) ^ ((row >> 1) & 3)) << 3) + (k & 7);
}

// async global->LDS, 16 B per lane; LDS dest = wave-uniform base + lane*16
DEVFN void gll16(const unsigned short* g, unsigned short* l) {
  __builtin_amdgcn_global_load_lds(
      (__attribute__((address_space(1))) void*)g,
      (__attribute__((address_space(3))) void*)l, 16, 0, 0);
}

// aux pointer bundle for fused A-staging modes
struct AuxP {
  const float* p0;
  const float* p1;
  const float* p2;
  const float* p3;
  const float* p4;
};

// ---------------------------------------------------------------------------
// AB GEMM (copy-mode K=128 NT=8): AB[z][N][256] = hbf @ preABT[z], fp16 out.
// grid 1024: z=bid>>8, y=(bid>>7)&1 (col half), xm=bid&127 (row tile).
// r1 sync structure; r11 coalesced LDS-repack epilogue.
// ---------------------------------------------------------------------------
__global__ __launch_bounds__(256) void ab_gemm(
    const unsigned short* __restrict__ hbf, const unsigned short* __restrict__ preABT_l,
    unsigned short* __restrict__ AB)
{
  __shared__ __align__(16) unsigned short S[16384]; // 32 KB staging; epilogue repack
  unsigned short* AhS = S;
  unsigned short* BhS = S + 8192;

  const int bid = blockIdx.x;
  const int z = bid >> 8, y = (bid >> 7) & 1, xm = bid & 127;
  const unsigned short* Wbase = preABT_l + (size_t)z * 256 * 128;
  unsigned short* Cu = AB + (size_t)z * NN * 256;
  const int bn = y * 128;
  const long long bm = (long long)xm * 128;

  const int tid = threadIdx.x;
  const int w = tid >> 6;
  const int lane = tid & 63;
  const int quad = lane >> 4;
  const int c16 = lane & 15;
  const int srow = lane >> 2;
  const int sslot = (lane & 3) << 3;

  f4 acc[2][8];
#pragma unroll
  for (int mt = 0; mt < 2; ++mt)
#pragma unroll
    for (int nt = 0; nt < 8; ++nt) acc[mt][nt] = (f4){0.f, 0.f, 0.f, 0.f};

  const unsigned short* whp = Wbase + (long long)(bn + srow) * 128 + sslot;
  const unsigned short* ahp = hbf + (bm + srow) * 128 + sslot;
  const int swr8 = ((quad ^ ((c16 >> 1) & 3)) << 3);

  auto stage = [&](int bi, int k0) {
#pragma unroll
    for (int ch = w; ch < 8; ch += 4) {
      gll16(ahp + (long long)ch * 16 * 128 + k0, AhS + bi * 4096 + ch * 512);
      gll16(whp + (long long)ch * 16 * 128 + k0, BhS + bi * 4096 + ch * 512);
    }
  };
  auto fragmfma = [&](int bi) {
    hfrag ah[2];
#pragma unroll
    for (int mt = 0; mt < 2; ++mt)
      ah[mt] = *(const hfrag*)&AhS[bi * 4096 + (w * 32 + mt * 16 + c16) * 32 + swr8];
#pragma unroll
    for (int nt = 0; nt < 8; ++nt) {
      hfrag bh = *(const hfrag*)&BhS[bi * 4096 + (nt * 16 + c16) * 32 + swr8];
#pragma unroll
      for (int mt = 0; mt < 2; ++mt)
        acc[mt][nt] = __builtin_amdgcn_mfma_f32_16x16x32_f16(ah[mt], bh, acc[mt][nt], 0, 0, 0);
    }
  };

  stage(0, 0);
  __syncthreads();
#pragma unroll
  for (int kt = 0; kt < 4; ++kt) {
    const int bi = kt & 1;
    if (kt < 3) stage(bi ^ 1, (kt + 1) << 5);
    fragmfma(bi);
    __syncthreads();
  }

  // epilogue: acc -> LDS [row][colLocal] fp16 -> coalesced 16B stores
#pragma unroll
  for (int nt = 0; nt < 8; ++nt) {
    const int colL = nt * 16 + c16;
#pragma unroll
    for (int mt = 0; mt < 2; ++mt) {
#pragma unroll
      for (int r = 0; r < 4; ++r) {
        const int row = w * 32 + mt * 16 + quad * 4 + r;
        S[row * 128 + colL] = f2h(acc[mt][nt][r]);
      }
    }
  }
  __syncthreads();
#pragma unroll
  for (int p = 0; p < 8; ++p) {
    const int row = p * 16 + (tid >> 4);
    const int co = (tid & 15) * 8;
    *(uint4*)&Cu[(bm + row) * 256 + bn + co] = *(const uint4*)&S[row * 128 + co];
  }
}

// ---------------------------------------------------------------------------
// Fused C-gemm + aggregation (deletes the Mb HBM round-trip, 134 MB/layer).
// grid (NN/16, 4 towers), 256 threads. Per block: nodes [n0,n0+16) whose CSR
// slots are contiguous [beg0,end0). Loop over 8-aligned 64-slot chunks:
//   phase A: MFMA C chunk = eaf[slots] @ foldT[z] + bfold  (identical fragment
//            structure / K-step order as the old C gemm -> bit-identical C),
//            written fp16 to a 16 KB LDS tile.
//   phase B: 16 node-walkers x 16 ch-lanes aggregate their node's slots within
//            the chunk: m = aval[n] + bval[esrc[slot]] + Cl[slot-c0]; same
//            4-slot batching and per-channel order as before (bit-identical).
// eaf is padded +128 rows so aligned chunk over-reads are safe; garbage C rows
// are computed but never aggregated. Output aggs fp16 [N][512] (swk).
// LDS 40 KB -> 4 blocks/CU.
// ---------------------------------------------------------------------------
__global__ __launch_bounds__(256) void aggc(
    const unsigned short* __restrict__ eaf, const unsigned short* __restrict__ foldT_l,
    const float* __restrict__ bfold_l, const unsigned short* __restrict__ ABb,
    const int* __restrict__ row_off, const int* __restrict__ esrc,
    unsigned short* __restrict__ aggs)
{
  __shared__ __align__(16) unsigned short AhS[2 * 2048]; // 64 rows x 32 k, dbuf
  __shared__ __align__(16) unsigned short BhS[2 * 4096]; // 128 cols x 32 k, dbuf
  __shared__ __align__(16) unsigned short Cl[64 * 128];  // C chunk, fp16

  const int z = blockIdx.y;
  const int n0 = blockIdx.x * 16;
  const unsigned short* W = foldT_l + (size_t)z * 128 * 128;
  const float* bias = bfold_l + z * 128;
  const unsigned short* ABs = ABb + (size_t)z * NN * 256;
  unsigned short* ag = aggs + (size_t)z * NN * 512;

  const int tid = threadIdx.x;
  const int w = tid >> 6;
  const int lane = tid & 63;
  const int quad = lane >> 4;
  const int c16 = lane & 15;
  const int srow = lane >> 2;
  const int sslot = (lane & 3) << 3;
  const int swr8 = ((quad ^ ((c16 >> 1) & 3)) << 3);

  const int beg0 = row_off[n0];
  const int end0 = row_off[n0 + 16];

  // walker state: node n, channels c8..c8+8
  const int wk = tid >> 4;            // 0..15 -> node
  const int c8 = (tid & 15) << 3;     // 8 channels
  const int n = n0 + wk;
  const int beg_n = row_off[n];
  const int end_n = row_off[n + 1];
  const int cnt = end_n - beg_n;
  float aval[8];
  ld8hf(&ABs[(long long)n * 256 + c8], aval);

  float sum[8], sq[8], mn[8], mx[8];
#pragma unroll
  for (int j = 0; j < 8; ++j) {
    sum[j] = 0.f; sq[j] = 0.f; mn[j] = INFINITY; mx[j] = -INFINITY;
  }
  auto upd = [&](const float* cv, const float* bv) {
#pragma unroll
    for (int j = 0; j < 8; ++j) {
      float m = aval[j] + bv[j] + cv[j];
      sum[j] += m; sq[j] += m * m;
      mn[j] = fminf(mn[j], m); mx[j] = fmaxf(mx[j], m);
    }
  };

  const unsigned short* whp = W + (long long)srow * 128 + sslot;

  for (int c0 = (beg0 & ~7); c0 < end0; c0 += 64) {
    // ---- phase A: C chunk via MFMA (rows = slots c0..c0+64) ----
    const unsigned short* ahp = eaf + (long long)(c0 + srow) * 128 + sslot;
    f4 acc[8];
#pragma unroll
    for (int nt = 0; nt < 8; ++nt) acc[nt] = (f4){0.f, 0.f, 0.f, 0.f};

    auto stage = [&](int bi, int k0) {
      // A: 64 rows; wave w stages rows 16w..16w+16 (one gll per lane)
      gll16(ahp + (long long)(w * 16) * 128 + k0, AhS + bi * 2048 + w * 512);
      // B: 128 cols
#pragma unroll
      for (int ch = w; ch < 8; ch += 4)
        gll16(whp + (long long)ch * 16 * 128 + k0, BhS + bi * 4096 + ch * 512);
    };
    stage(0, 0);
    __syncthreads();
#pragma unroll
    for (int kt = 0; kt < 4; ++kt) {
      const int bi = kt & 1;
      if (kt < 3) stage(bi ^ 1, (kt + 1) << 5);
      hfrag ah = *(const hfrag*)&AhS[bi * 2048 + (w * 16 + c16) * 32 + swr8];
#pragma unroll
      for (int nt = 0; nt < 8; ++nt) {
        hfrag bh = *(const hfrag*)&BhS[bi * 4096 + (nt * 16 + c16) * 32 + swr8];
        acc[nt] = __builtin_amdgcn_mfma_f32_16x16x32_f16(ah, bh, acc[nt], 0, 0, 0);
      }
      __syncthreads();
    }
    // write C chunk to LDS (row = w*16+quad*4+r local slot, col = nt*16+c16)
#pragma unroll
    for (int nt = 0; nt < 8; ++nt) {
      const int col = nt * 16 + c16;
      const float bv = bias[col];
#pragma unroll
      for (int r = 0; r < 4; ++r)
        Cl[(w * 16 + quad * 4 + r) * 128 + col] = f2h(acc[nt][r] + bv);
    }
    __syncthreads();

    // ---- phase B: aggregate this chunk's slice of each walker's node ----
    const int ce = c0 + 64;
    const int sb = max(beg_n, c0);
    const int se = min(end_n, ce);
    for (int s0 = sb; s0 < se; s0 += 4) {
      const int e1 = min(s0 + 1, se - 1);
      const int e2 = min(s0 + 2, se - 1);
      const int e3 = min(s0 + 3, se - 1);
      const int sA = esrc[s0], sB = esrc[e1], sC = esrc[e2], sD = esrc[e3];
      float cA[8], cB[8], cC[8], cD[8], bA[8], bB[8], bC[8], bD[8];
      ld8hf(&Cl[(s0 - c0) * 128 + c8], cA);
      ld8hf(&Cl[(e1 - c0) * 128 + c8], cB);
      ld8hf(&Cl[(e2 - c0) * 128 + c8], cC);
      ld8hf(&Cl[(e3 - c0) * 128 + c8], cD);
      ld8hf(&ABs[(long long)sA * 256 + 128 + c8], bA);
      ld8hf(&ABs[(long long)sB * 256 + 128 + c8], bB);
      ld8hf(&ABs[(long long)sC * 256 + 128 + c8], bC);
      ld8hf(&ABs[(long long)sD * 256 + 128 + c8], bD);
      upd(cA, bA);
      if (s0 + 1 < se) upd(cB, bB);
      if (s0 + 2 < se) upd(cC, bC);
      if (s0 + 3 < se) upd(cD, bD);
    }
    __syncthreads(); // Cl / staging reused next chunk
  }

  const float degc = fmaxf((float)cnt, 1.0f);
  const float inv = 1.0f / degc;
  us8v omean, omin, omax, ostd;
#pragma unroll
  for (int j = 0; j < 8; ++j) {
    float mean = sum[j] * inv;
    float var = sq[j] * inv - mean * mean;
    float stdv = sqrtf(fmaxf(var, 0.f) + 1e-5f);
    omean[j] = f2h(mean);
    omin[j] = f2h((cnt > 0) ? mn[j] : 0.f);
    omax[j] = f2h((cnt > 0) ? mx[j] : 0.f);
    ostd[j] = f2h(stdv);
  }
  const int sc = swk(n, c8);
  const long long base = (long long)n * 512 + sc;
  *(us8v*)&ag[base] = omean;
  *(us8v*)&ag[base + 128] = omin;
  *(us8v*)&ag[base + 256] = omax;
  *(us8v*)&ag[base + 384] = ostd;
}

// ---------------------------------------------------------------------------
// fp16 MFMA GEMM (templated modes): C[M,Nc] = A[M,K] @ W[K,Nc], fp32 acc.
// A-staging modes (ASRC):
//   1: fp16 ushort input (pre-swizzled), gll copy       [P gemm]
//   3: lin-fused: K=256 two-phase. k<128: A = P_id + s*P_amp + invs*P_att +
//      bpost (ds-write; p0=P fp16, p2=s, p3=invs, p4=bpost). k>=128: A = hbf
//      (Av, gll copy) vs folded Wx@Wlin half of B. Epilogue accumulates BN
//      column stats into p1 (colsum|colsq).
//   4: fp32 / rowcount (p0=cntf) -- global mean pool divide (ds-write)
// OHALF: epilogue stores fp16. NT = column fragments. r1 sync structure.
// ---------------------------------------------------------------------------
template <int ASRC, int NT, bool BIAS, bool RELU, bool OHALF>
__global__ __launch_bounds__(256) void mgemm(
    const void* __restrict__ Av, const unsigned short* __restrict__ WT,
    const float* __restrict__ bias,
    float* __restrict__ C, AuxP aux,
    int Nc, int K, int lda, int ldc,
    long long bsA, long long bsW, long long bsC, int bsBias)
{
  constexpr bool COPYA = (ASRC == 1);
  constexpr int BST = NT * 16 * 32; // ushorts per B buffer

  const int z = blockIdx.z;
  WT += (long long)z * bsW;
  if (BIAS) bias += (long long)z * bsBias;
  float* Cf = C + (OHALF ? 0 : (long long)z * bsC);
  unsigned short* Cu = (unsigned short*)C + (OHALF ? (long long)z * bsC : 0);

  __shared__ __align__(16) unsigned short AhS[2 * 128 * 32];
  __shared__ __align__(16) unsigned short BhS[2 * BST];

  const int tid = threadIdx.x;
  const long long bm = (long long)blockIdx.x * 128;
  const int bn = blockIdx.y * (NT * 16);
  const int w = tid >> 6;
  const int lane = tid & 63;
  const int quad = lane >> 4;
  const int c16 = lane & 15;
  const int srow = lane >> 2;        // staging row within 16-row chunk
  const int sslot = (lane & 3) << 3; // staging slot (ushort offset)

  // ds-write-mode indices: each thread produces 16 A elements of one row-half
  const int arow = tid >> 1;
  const int sel = tid & 1;
  const long long rowsrc = bm + arow;

  f4 acc[2][NT];
#pragma unroll
  for (int mt = 0; mt < 2; ++mt)
#pragma unroll
    for (int nt = 0; nt < NT; ++nt) acc[mt][nt] = (f4){0.f, 0.f, 0.f, 0.f};

  // lane-invariant staging bases
  const unsigned short* whp = WT + (long long)(bn + srow) * K + sslot;

  const unsigned short* ahp = nullptr;
  if (COPYA || ASRC == 3)
    ahp = (const unsigned short*)Av + (long long)z * bsA + (bm + srow) * (long long)lda + sslot;

  // ds-write-mode A state (ASRC 3 / 4)
  float invdc = 1.f;
  float sv = 0.f, iv = 0.f;
  const float* apA = nullptr;
  const unsigned short* Prow_base = nullptr;
  if (ASRC == 3) {
    Prow_base = (const unsigned short*)aux.p0 + rowsrc * 384;
    sv = aux.p2[rowsrc];
    iv = aux.p3[rowsrc];
  } else if (ASRC == 4) {
    apA = (const float*)Av + (long long)z * bsA + rowsrc * lda;
    invdc = 1.f / fmaxf(aux.p0[rowsrc], 1.f);
  }
  // swizzled LDS write offsets for ds-write-mode A
  const int swa = (arow >> 1) & 3;
  const int s0us = arow * 32 + (((2 * sel) ^ swa) << 3);
  const int s1us = arow * 32 + (((2 * sel + 1) ^ swa) << 3);

  // fragment-read swizzle: slot quad ^ ((row>>1)&3); row bits 1..2 == c16 bits
  const int swr8 = ((quad ^ ((c16 >> 1) & 3)) << 3);

  auto stageB = [&](int bi, int k0) {
#pragma unroll
    for (int ch = w; ch < NT; ch += 4)
      gll16(whp + (long long)ch * 16 * K + k0, BhS + bi * BST + ch * 512);
  };
  auto stageA = [&](int bi, int k0) { // gll copy of A rows (k0 relative to lda)
#pragma unroll
    for (int ch = w; ch < 8; ch += 4)
      gll16(ahp + (long long)ch * 16 * lda + k0, AhS + bi * 4096 + ch * 512);
  };
  auto stageLoad = [&](int k0, float* va) {
    const int ck0 = k0 + sel * 16;
    if (ASRC == 3) {
      const unsigned short* Prow = Prow_base + ((ck0 >> 5) * 96) + (ck0 & 31);
      float pid[16], pam[16], pat[16];
      ld8hf(Prow, pid); ld8hf(Prow + 8, pid + 8);
      ld8hf(Prow + 32, pam); ld8hf(Prow + 40, pam + 8);
      ld8hf(Prow + 64, pat); ld8hf(Prow + 72, pat + 8);
#pragma unroll
      for (int i = 0; i < 16; ++i)
        va[i] = pid[i] + sv * pam[i] + iv * pat[i] + aux.p4[ck0 + i];
    } else {
      *(float4*)&va[0] = *(const float4*)(apA + ck0);
      *(float4*)&va[4] = *(const float4*)(apA + ck0 + 4);
      *(float4*)&va[8] = *(const float4*)(apA + ck0 + 8);
      *(float4*)&va[12] = *(const float4*)(apA + ck0 + 12);
    }
  };
  auto stageWrite = [&](int bi, const float* va) {
    hfrag hv0, hv1;
#pragma unroll
    for (int i = 0; i < 16; ++i) {
      float x = va[i];
      if (ASRC == 4) x *= invdc;
      if (i < 8) hv0[i] = (_Float16)x;
      else       hv1[i - 8] = (_Float16)x;
    }
    *(hfrag*)&AhS[bi * 4096 + s0us] = hv0;
    *(hfrag*)&AhS[bi * 4096 + s1us] = hv1;
  };
  auto fragmfma = [&](int bi) {
    hfrag ah[2];
#pragma unroll
    for (int mt = 0; mt < 2; ++mt) {
      const int r = w * 32 + mt * 16 + c16;
      ah[mt] = *(const hfrag*)&AhS[bi * 4096 + r * 32 + swr8];
    }
#pragma unroll
    for (int nt = 0; nt < NT; ++nt) {
      const int r = nt * 16 + c16;
      hfrag bh = *(const hfrag*)&BhS[bi * BST + r * 32 + swr8];
#pragma unroll
      for (int mt = 0; mt < 2; ++mt)
        acc[mt][nt] = __builtin_amdgcn_mfma_f32_16x16x32_f16(ah[mt], bh, acc[mt][nt], 0, 0, 0);
    }
  };

  float va[16];
  const int nk = K >> 5;

  // prologue: fill buffer 0 (ASRC3's tile 0 is ds-mode)
  if (COPYA) {
    stageA(0, 0);
    stageB(0, 0);
  } else {
    stageLoad(0, va);
    stageB(0, 0);
    stageWrite(0, va);
  }
  __syncthreads();

  for (int kt = 0; kt < nk; ++kt) {
    const int bi = kt & 1;
    const bool pf = (kt + 1 < nk);
    bool nextds = false;
    if (pf) {
      const int k0 = (kt + 1) << 5;
      stageB(bi ^ 1, k0);
      if (COPYA) {
        stageA(bi ^ 1, k0);
      } else if (ASRC == 3 && k0 >= 128) {
        stageA(bi ^ 1, k0 - 128); // copy phase: A = hbf (x-through path)
      } else {
        stageLoad(k0, va);
        nextds = true;
      }
    }
    fragmfma(bi);
    if (nextds) stageWrite(bi ^ 1, va);
    __syncthreads();
  }

  // epilogue: C/D layout col=lane&15, row=quad*4+reg
  float ls[NT], lq[NT];
#pragma unroll
  for (int nt = 0; nt < NT; ++nt) { ls[nt] = 0.f; lq[nt] = 0.f; }
#pragma unroll
  for (int nt = 0; nt < NT; ++nt) {
    int col = bn + nt * 16 + c16;
    if (col >= Nc) continue;
    float bv = BIAS ? bias[col] : 0.f;
#pragma unroll
    for (int mt = 0; mt < 2; ++mt) {
#pragma unroll
      for (int r = 0; r < 4; ++r) {
        long long row = bm + w * 32 + mt * 16 + quad * 4 + r;
        float v = acc[mt][nt][r] + bv;
        if (RELU) v = fmaxf(v, 0.f);
        if (ASRC == 3) { ls[nt] += v; lq[nt] += v * v; }
        if (OHALF) Cu[row * ldc + col] = f2h(v);
        else Cf[row * ldc + col] = v;
      }
    }
  }
  if constexpr (ASRC == 3) {
    // fused BN column partial stats: LDS reduce + one global atomic per col
    float* csum = (float*)AhS;  // reuse LDS (all waves past final barrier)
    float* csq = csum + 128;
    if (tid < 128) { csum[tid] = 0.f; csq[tid] = 0.f; }
    __syncthreads();
#pragma unroll
    for (int nt = 0; nt < NT; ++nt) {
      int col = bn + nt * 16 + c16;
      atomicAdd(&csum[col], ls[nt]);
      atomicAdd(&csq[col], lq[nt]);
    }
    __syncthreads();
    float* colsum = (float*)aux.p1;
    if (tid < 128) {
      atomicAdd(&colsum[tid], csum[tid]);
      atomicAdd(&colsum[128 + tid], csq[tid]);
    }
  }
}

// ---------------------------------------------------------------------------
// edge encoder: fp16 DIRECTLY in CSR slot order, PRE-SWIZZLED; 2 edges/block
// ---------------------------------------------------------------------------
__global__ __launch_bounds__(256) void edge_enc(
    const float* __restrict__ eat, const float* __restrict__ We,
    const float* __restrict__ be, const int* __restrict__ slot_of,
    unsigned short* __restrict__ ef)
{
  int e = blockIdx.x * 2 + (threadIdx.x >> 7);
  int c = threadIdx.x & 127;
  float acc = be[c];
#pragma unroll
  for (int k = 0; k < 4; ++k) acc += eat[e * 4 + k] * We[k * 128 + c];
  long long slot = slot_of[e];
  ef[slot * 128 + swk((int)slot, c)] = f2h(fmaxf(acc, 0.f));
}

// ---------------------------------------------------------------------------
// CSR build: count -> scan (also inits cursor + s/invs) -> scatter
// ---------------------------------------------------------------------------
__global__ void count_deg(const int* __restrict__ dst, int* __restrict__ degi)
{
  int e = blockIdx.x * 256 + threadIdx.x;
  if (e < EE) atomicAdd(&degi[dst[e]], 1);
}

__global__ __launch_bounds__(1024) void scan_k(const int* __restrict__ degi,
                                               int* __restrict__ row_off,
                                               int* __restrict__ cursor,
                                               float* __restrict__ s_arr,
                                               float* __restrict__ invs)
{
  __shared__ int tsum[1024];
  int t = threadIdx.x;
  int local[16];
  int base = t * 16;
  int s = 0;
#pragma unroll
  for (int i = 0; i < 16; ++i) { local[i] = s; s += degi[base + i]; }
  tsum[t] = s;
  __syncthreads();
  for (int off = 1; off < 1024; off <<= 1) {
    int v = (t >= off) ? tsum[t - off] : 0;
    __syncthreads();
    tsum[t] += v;
    __syncthreads();
  }
  int prev = (t == 0) ? 0 : tsum[t - 1];
#pragma unroll
  for (int i = 0; i < 16; ++i) {
    int start = prev + local[i];
    row_off[base + i] = start;
    cursor[base + i] = start;
    int cnt = degi[base + i];
    float degc = fmaxf((float)cnt, 1.f);
    float sv = logf(degc + 1.f) / AVG_LOG_F;
    s_arr[base + i] = sv;
    invs[base + i] = 1.f / sv;
  }
  if (t == 1023) row_off[NN] = tsum[1023];
}

__global__ void scatter_k(const int* __restrict__ src, const int* __restrict__ dst,
                          int* __restrict__ cursor,
                          int* __restrict__ slot_of, int* __restrict__ esrc)
{
  int e = blockIdx.x * 256 + threadIdx.x;
  if (e >= EE) return;
  int d = dst[e];
  int slot = atomicAdd(&cursor[d], 1);
  slot_of[e] = slot;
  esrc[slot] = src[e];
}

// ---------------------------------------------------------------------------
// Weight folds (fp32)
// ---------------------------------------------------------------------------
__global__ __launch_bounds__(512) void fold_w(const float* __restrict__ We_conv,
                                              const float* __restrict__ Wpre,
                                              float* __restrict__ Wfold)
{
  int k = blockIdx.x & 127, l = blockIdx.x >> 7;
  int t = threadIdx.x >> 7, f = threadIdx.x & 127;
  const float* wc = We_conv + (long long)(l * 128 + k) * 128;
  const float* wp = Wpre + ((long long)((l * 4 + t) * 384 + 256)) * 128 + f;
  float acc = 0.f;
  for (int j = 0; j < 128; ++j) acc += wc[j] * wp[(long long)j * 128];
  Wfold[((long long)(l * 128 + k)) * 512 + threadIdx.x] = acc;
}

__global__ __launch_bounds__(512) void fold_b(const float* __restrict__ be_conv,
                                              const float* __restrict__ Wpre,
                                              const float* __restrict__ bpre,
                                              float* __restrict__ bfold)
{
  int l = blockIdx.x;
  int t = threadIdx.x >> 7, f = threadIdx.x & 127;
  const float* bc = be_conv + l * 128;
  const float* wp = Wpre + ((long long)((l * 4 + t) * 384 + 256)) * 128 + f;
  float acc = bpre[(l * 4 + t) * 128 + f];
  for (int j = 0; j < 128; ++j) acc += bc[j] * wp[(long long)j * 128];
  bfold[l * 512 + threadIdx.x] = acc;
}

// ---------------------------------------------------------------------------
// pack_all: ALL fp32 -> fp16 swizzled packers + node encoder in ONE launch.
// Segments by blockIdx (128 threads each):
//  [0,3072)      preABT[lt][n(256)][k(128)]
//  [3072,4608)   foldT[lt][n(128)][k(128)]   (reads WfoldF, after fold_w)
//  [4608,6144)   post3T[lt][c(128)][r(512)]  (4 r per thread)
//  [6144,6528)   linT2 lo-half: Wlin transpose [l][n][k<128]
//  [6528,6912)   linT2 hi-half: Wxl[l][o][128+kk] = sum_c Wx[kk][c]*Wlin[c][o]
//  [6912,6976)   w1T[n(64)][k(128)]
//  [6976,23360)  node_enc: hbf[n] = fp16(relu(x@Wa+ba)) swizzled
// ---------------------------------------------------------------------------
__global__ __launch_bounds__(128) void pack_all(
    const float* __restrict__ Wpre, const float* __restrict__ WfoldF,
    const float* __restrict__ Wpost, const float* __restrict__ Wlin,
    const float* __restrict__ W1,
    const float* __restrict__ x, const float* __restrict__ Wa,
    const float* __restrict__ ba,
    unsigned short* __restrict__ preABT, unsigned short* __restrict__ foldT,
    unsigned short* __restrict__ post3T, unsigned short* __restrict__ linT2,
    unsigned short* __restrict__ w1T, unsigned short* __restrict__ hbf)
{
  const int b = blockIdx.x;
  const int t = threadIdx.x;
  if (b < 3072) {                       // preABT
    int lt = b >> 8, n = b & 255, k = t;
    int row = (n < 128) ? k : (128 + k);
    int f = n & 127;
    float v = Wpre[((long long)(lt * 384 + row)) * 128 + f];
    preABT[((long long)(lt * 256 + n)) * 128 + swk(n, k)] = f2h(v);
  } else if (b < 4608) {                // foldT
    int b2 = b - 3072;
    int lt = b2 >> 7, n = b2 & 127, k = t;
    int l = lt >> 2, tw = lt & 3;
    float v = WfoldF[((long long)(l * 128 + k)) * 512 + tw * 128 + n];
    foldT[((long long)(lt * 128 + n)) * 128 + swk(n, k)] = f2h(v);
  } else if (b < 6144) {                // post3T
    int b3 = b - 4608;
    int lt = b3 >> 7, c = b3 & 127;
#pragma unroll
    for (int j = 0; j < 4; ++j) {
      int r = t + 128 * j;
      float v = 0.f;
      if (c < 96)
        v = Wpost[((long long)(lt * 1664 + 128 + (c >> 5) * 512 + r)) * 32 + (c & 31)];
      post3T[((long long)(lt * 128 + c)) * 512 + swk(c, r)] = f2h(v);
    }
  } else if (b < 6528) {                // linT2 low half: Wlin^T
    int b4 = b - 6144;
    int l = b4 >> 7, n = b4 & 127, k = t;
    float v = Wlin[((long long)(l * 128 + k)) * 128 + n];
    linT2[((long long)(l * 128 + n)) * 256 + swk(n, k)] = f2h(v);
  } else if (b < 6912) {                // linT2 high half: Wxl fold
    int b5 = b - 6528;
    int l = b5 >> 7, kk = b5 & 127, o = t;
    float acc = 0.f;
    for (int c = 0; c < 128; ++c) {
      float wx = Wpost[((long long)((l * 4 + (c >> 5)) * 1664 + kk)) * 32 + (c & 31)];
      acc += wx * Wlin[((long long)(l * 128 + c)) * 128 + o];
    }
    linT2[((long long)(l * 128 + o)) * 256 + swk(o, 128 + kk)] = f2h(acc);
  } else if (b < 6976) {                // w1T
    int n = b - 6912, k = t;
    w1T[(long long)n * 128 + swk(n, k)] = f2h(W1[k * 64 + n]);
  } else {                              // node_enc
    int n = b - 6976, c = t;
    float acc = ba[c];
#pragma unroll
    for (int k = 0; k < 11; ++k) acc += x[n * 11 + k] * Wa[k * 128 + c];
    hbf[((long long)n << 7) + swk(n, c)] = f2h(fmaxf(acc, 0.f));
  }
}

// ---------------------------------------------------------------------------
// BN apply (coef computed inline from colstats)
// hb = fp16(relu(hn*scale + shift)) pre-swizzled; hn is fp16
// ---------------------------------------------------------------------------
__global__ __launch_bounds__(256) void bn_apply(const unsigned short* __restrict__ hn,
                                                const float* __restrict__ cs,
                                                const float* __restrict__ g,
                                                const float* __restrict__ b,
                                                unsigned short* __restrict__ hb)
{
  int idx = blockIdx.x * 256 + threadIdx.x; // n*128+c
  int c = idx & 127, n = idx >> 7;
  float mean = cs[c] * (1.f / 16384.f);
  float var = cs[128 + c] * (1.f / 16384.f) - mean * mean;
  float sc = g[c] * rsqrtf(var + 1e-5f);
  float v = fmaxf(h2f(hn[idx]) * sc + (b[c] - mean * sc), 0.f);
  hb[((long long)n << 7) + swk(n, c)] = f2h(v);
}

// ---------------------------------------------------------------------------
// Global mean pool (BN+ReLU fused) + head
// ---------------------------------------------------------------------------
__global__ void pool_add(const unsigned short* __restrict__ y, const float* __restrict__ cs,
                         const float* __restrict__ g, const float* __restrict__ b,
                         const int* __restrict__ batch,
                         float* __restrict__ pooled, float* __restrict__ cntf)
{
  int n = blockIdx.x, c = threadIdx.x;
  float mean = cs[c] * (1.f / 16384.f);
  float var = cs[128 + c] * (1.f / 16384.f) - mean * mean;
  float v = fmaxf((h2f(y[(long long)n * 128 + c]) - mean) * rsqrtf(var + 1e-5f) * g[c] + b[c], 0.f);
  int bb = batch[n];
  atomicAdd(&pooled[(long long)bb * 128 + c], v);
  if (c == 0) atomicAdd(&cntf[bb], 1.f);
}

__global__ __launch_bounds__(256) void zstats(const float* __restrict__ z,
                                              float* __restrict__ zm, float* __restrict__ zv)
{
  int j = blockIdx.x; // 64 cols
  float s = 0.f, q = 0.f;
  for (int g = threadIdx.x; g < GG; g += 256) {
    float v = z[g * 64 + j];
    s += v;
    q += v * v;
  }
  __shared__ float ps[256], pq[256];
  ps[threadIdx.x] = s;
  pq[threadIdx.x] = q;
  __syncthreads();
  for (int st = 128; st > 0; st >>= 1) {
    if (threadIdx.x < st) {
      ps[threadIdx.x] += ps[threadIdx.x + st];
      pq[threadIdx.x] += pq[threadIdx.x + st];
    }
    __syncthreads();
  }
  if (threadIdx.x == 0) {
    float m = ps[0] / (float)GG;
    zm[j] = m;
    zv[j] = pq[0] / (float)GG - m * m;
  }
}

__global__ void final_out(const float* __restrict__ z, const float* __restrict__ zm,
                          const float* __restrict__ zv, const float* __restrict__ hg,
                          const float* __restrict__ hb, const float* __restrict__ W2,
                          const float* __restrict__ b2, float* __restrict__ out)
{
  int g = blockIdx.x;
  int j = threadIdx.x; // 64 = one wave
  float v = (z[g * 64 + j] - zm[j]) * rsqrtf(zv[j] + 1e-5f) * hg[j] + hb[j];
  float t = v * W2[j];
#pragma unroll
  for (int off = 32; off > 0; off >>= 1) t += __shfl_down(t, off);
  if (j == 0) out[g] = t + b2[0];
}

// ---------------------------------------------------------------------------
extern "C" void kernel_launch(void* const* d_in, const int* in_sizes, int n_in,
                              void* d_out, int out_size, void* d_ws, size_t ws_size,
                              hipStream_t stream)
{
  (void)in_sizes; (void)n_in; (void)out_size;
  const float* x = (const float*)d_in[0];
  const float* eat = (const float*)d_in[1];
  const int* ei = (const int*)d_in[2];
  const int* batch = (const int*)d_in[3];
  const float* Wa = (const float*)d_in[4];
  const float* ba = (const float*)d_in[5];
  const float* We = (const float*)d_in[6];
  const float* be = (const float*)d_in[7];
  const float* We_conv = (const float*)d_in[8];
  const float* be_conv = (const float*)d_in[9];
  const float* Wpre = (const float*)d_in[10];
  const float* bpre = (const float*)d_in[11];
  const float* Wpost = (const float*)d_in[12];
  const float* bpost = (const float*)d_in[13];
  const float* Wlin = (const float*)d_in[14];
  const float* blin = (const float*)d_in[15];
  const float* bng = (const float*)d_in[16];
  const float* bnb = (const float*)d_in[17];
  const float* W1 = (const float*)d_in[18];
  const float* b1 = (const float*)d_in[19];
  const float* hg = (const float*)d_in[20];
  const float* hb = (const float*)d_in[21];
  const float* W2 = (const float*)d_in[22];
  const float* b2 = (const float*)d_in[23];
  float* out = (float*)d_out;

  const int* srcI = ei;
  const int* dstI = ei + EE;

  char* ws = (char*)d_ws;
  size_t off = 0;
  auto alloc = [&](size_t bytes) -> char* {
    char* p = ws + off;
    off += (bytes + 255) & ~(size_t)255;
    return p;
  };

  unsigned short* hbf = (unsigned short*)alloc((size_t)NN * 128 * 2); // fp16 h
  unsigned short* hn = (unsigned short*)alloc((size_t)NN * 128 * 2);  // fp16 hn
  unsigned short* eaf = (unsigned short*)alloc((size_t)(EE + 128) * 128 * 2); // fp16 ea +pad
  unsigned short* AB = (unsigned short*)alloc((size_t)4 * NN * 256 * 2); // fp16 [T][N][256]
  unsigned short* P = (unsigned short*)alloc((size_t)NN * 384 * 2);   // fp16 [N][384]
  unsigned short* aggt = (unsigned short*)alloc((size_t)4 * NN * 512 * 2); // fp16 [T][N][512]
  float* s_arr = (float*)alloc((size_t)NN * 4);
  float* invs = (float*)alloc((size_t)NN * 4);
  int* degi = (int*)alloc((size_t)NN * 4);
  int* cursor = (int*)alloc((size_t)NN * 4);
  int* row_off = (int*)alloc((size_t)(NN + 1) * 4);
  int* slot_of = (int*)alloc((size_t)EE * 4);
  int* esrc = (int*)alloc((size_t)EE * 4);
  float* WfoldF = (float*)alloc((size_t)3 * 128 * 512 * 4);
  float* bfold = (float*)alloc((size_t)3 * 512 * 4);
  unsigned short* preABT = (unsigned short*)alloc((size_t)12 * 256 * 128 * 2);
  unsigned short* foldT = (unsigned short*)alloc((size_t)12 * 128 * 128 * 2);
  unsigned short* post3T = (unsigned short*)alloc((size_t)12 * 128 * 512 * 2);
  unsigned short* linT2 = (unsigned short*)alloc((size_t)3 * 128 * 256 * 2); // [Wlin^T | Wx@Wlin]
  unsigned short* w1T = (unsigned short*)alloc((size_t)64 * 128 * 2);
  float* colstats = (float*)alloc(3 * 256 * 4); // one 256-buffer per layer
  float* pooled = (float*)alloc((size_t)GG * 128 * 4);
  float* cntf = (float*)alloc((size_t)GG * 4);
  float* zbuf = (float*)alloc((size_t)GG * 64 * 4);
  float* zm = (float*)alloc(64 * 4);
  float* zv = (float*)alloc(64 * 4);

  if (off > ws_size) return; // bail rather than corrupt

  // ---- graph structure ----
  hipMemsetAsync(degi, 0, (size_t)NN * 4, stream);
  hipMemsetAsync(colstats, 0, 3 * 256 * 4, stream);
  count_deg<<<EE / 256, 256, 0, stream>>>(dstI, degi);
  scan_k<<<1, 1024, 0, stream>>>(degi, row_off, cursor, s_arr, invs);
  scatter_k<<<EE / 256, 256, 0, stream>>>(srcI, dstI, cursor, slot_of, esrc);

  // ---- encoders + weight folds/packing ----
  edge_enc<<<EE / 2, 256, 0, stream>>>(eat, We, be, slot_of, eaf); // after scatter_k
  fold_w<<<384, 512, 0, stream>>>(We_conv, Wpre, WfoldF);
  fold_b<<<3, 512, 0, stream>>>(be_conv, Wpre, bpre, bfold);
  pack_all<<<6976 + NN, 128, 0, stream>>>(Wpre, WfoldF, Wpost, Wlin, W1, x, Wa, ba,
                                          preABT, foldT, post3T, linT2, w1T, hbf);

  for (int l = 0; l < 3; ++l) {
    float* cs_l = colstats + l * 256;
    // AB gemm (z=4, both col-halves), one dispatch
    ab_gemm<<<1024, 256, 0, stream>>>(hbf, preABT + (size_t)l * 4 * 256 * 128, AB);
    // fused C-gemm + aggregation (no Mb round trip)
    aggc<<<dim3(NN / 16, 4), 256, 0, stream>>>(
        eaf, foldT + (size_t)l * 4 * 128 * 128, bfold + l * 512,
        AB, row_off, esrc, aggt);
    // P all towers: fp16 [N,512] @ [512,96] (z=4, exact 96-col tile) -> fp16 P
    mgemm<1, 6, false, false, true><<<dim3(NN / 128, 1, 4), 256, 0, stream>>>(
        aggt, post3T + (size_t)l * 4 * 128 * 512, nullptr, (float*)P, AuxP{},
        96, 512, 512, 384, (long long)NN * 512, (long long)128 * 512, 96, 0);
    // lin (K=256 two-phase: P-combine | hbf x-through vs folded Wx@Wlin),
    // + blin; epilogue fuses BN column stats into cs_l; output fp16 hn
    mgemm<3, 8, true, false, true><<<dim3(NN / 128, 1, 1), 256, 0, stream>>>(
        hbf, linT2 + (size_t)l * 128 * 256, blin + l * 128, (float*)hn,
        AuxP{(const float*)P, cs_l, s_arr, invs, bpost + l * 128},
        128, 256, 128, 128, 0, 0, 0, 0);
    if (l < 2)
      bn_apply<<<NN * 128 / 256, 256, 0, stream>>>(hn, cs_l, bng + l * 128,
                                                   bnb + l * 128, hbf);
  }

  // ---- pooling (BN+ReLU fused) + head ----
  hipMemsetAsync(pooled, 0, (size_t)GG * 128 * 4, stream);
  hipMemsetAsync(cntf, 0, (size_t)GG * 4, stream);
  pool_add<<<NN, 128, 0, stream>>>(hn, colstats + 2 * 256,
                                   bng + 2 * 128, bnb + 2 * 128, batch, pooled, cntf);
  mgemm<4, 4, true, true, false><<<dim3(GG / 128, 1, 1), 256, 0, stream>>>(
      pooled, w1T, b1, zbuf, AuxP{cntf, nullptr, nullptr, nullptr, nullptr},
      64, 128, 128, 64, 0, 0, 0, 0);
  zstats<<<64, 256, 0, stream>>>(zbuf, zm, zv);
  final_out<<<GG, 64, 0, stream>>>(zbuf, zm, zv, hg, hb, W2, b2, out);
}

// Round 13
// 559.636 us; speedup vs baseline: 1.1981x; 1.1981x over previous
//
#include <hip/hip_runtime.h>
#include <hip/hip_bf16.h>

#define DEVFN static __device__ __forceinline__

constexpr int NN = 16384;
constexpr int EE = 65536;
constexpr int GG = 512;
constexpr float AVG_LOG_F = 1.0227308671603782f; // (sum d*log d, d=1..4, hist 1,2,3,4)/10

typedef _Float16 hfrag __attribute__((ext_vector_type(8))); // 8 fp16 = 4 VGPR (MFMA A/B)
typedef __attribute__((ext_vector_type(4))) float f4;       // MFMA C/D
typedef __attribute__((ext_vector_type(8))) unsigned short us8v; // 16B fp16 vector

// fp32 <-> fp16 (RNE, native v_cvt). Measured (r5-r8): bf16 slabs +0.0097
// absmax; fp16 slabs noise-level. All intermediates + GEMM operands fp16.
DEVFN unsigned short f2h(float f) {
  _Float16 h = (_Float16)f;
  unsigned short r; __builtin_memcpy(&r, &h, 2); return r;
}
DEVFN float h2f(unsigned short s) {
  _Float16 h; __builtin_memcpy(&h, &s, 2); return (float)h;
}

// load 8 fp16 (single 16B) -> float[8]
DEVFN void ld8hf(const unsigned short* p, float* o) {
  us8v v = *(const us8v*)p;
#pragma unroll
  for (int i = 0; i < 8; ++i) o[i] = h2f(v[i]);
}

// XOR swizzle for packed fp16 [R][K] operand arrays staged with global_load_lds:
// element (row,k) lives at row*K + swk(row,k). Within each 32-wide K window the
// four 8-element slots are permuted by (row>>1)&3 so a wave's ds_read_b128
// fragment reads become a permutation of a contiguous 1 KB region ->
// bank-conflict-free. global_load_lds copies LINEARLY, so the swizzle is baked
// into the packed global layout (both-sides rule, #21).
DEVFN int swk(int row, int k) {
  return (k & ~31) + ((((k >> 3) & 3) ^ ((row >> 1) & 3)) << 3) + (k & 7);
}

// async global->LDS, 16 B per lane; LDS dest = wave-uniform base + lane*16
DEVFN void gll16(const unsigned short* g, unsigned short* l) {
  __builtin_amdgcn_global_load_lds(
      (__attribute__((address_space(1))) void*)g,
      (__attribute__((address_space(3))) void*)l, 16, 0, 0);
}

// aux pointer bundle for fused A-staging modes
struct AuxP {
  const float* p0;
  const float* p1;
  const float* p2;
  const float* p3;
  const float* p4;
};

// ---------------------------------------------------------------------------
// Merged AB + C GEMM (one dispatch per layer; both are copy-mode K=128 NT=8).
// XCD-aware block swizzle (grid 3072 % 8 == 0 -> bijective): hardware
// round-robins blockIdx across 8 XCDs; wid=(bid&7)*384+(bid>>3) gives each
// XCD a contiguous work range so blocks sharing a tower's weight panel and
// A-row stripes co-reside in one XCD's L2 (r12 post-mortem: abc is 47%
// HBM-bound -> T1's regime).
//  wid < 1024 : AB role. A = hbf [N,128]; W = preABT tower z; out fp16
//               AB[z][N][256]. (z=wid>>8, y=(wid>>7)&1, xm=wid&127)
//  wid >= 1024: C role.  A = eaf [E,128] (CSR order); W = foldT tower z;
//               out fp16 Mb[z][E][128], bias=bfold. (z=idx>>9, xm=idx&511)
// r1 sync structure; r11 coalesced LDS-repack epilogue (2B scalar stores cost
// +27% WRITE_SIZE per r10 PMC).
// ---------------------------------------------------------------------------
__global__ __launch_bounds__(256) void abc_gemm(
    const unsigned short* __restrict__ hbf, const unsigned short* __restrict__ preABT_l,
    unsigned short* __restrict__ AB,
    const unsigned short* __restrict__ eaf, const unsigned short* __restrict__ foldT_l,
    const float* __restrict__ bfold_l, unsigned short* __restrict__ Mb)
{
  __shared__ __align__(16) unsigned short S[16384]; // 32 KB staging; epilogue repack
  unsigned short* AhS = S;
  unsigned short* BhS = S + 8192;

  const int bid = (blockIdx.x & 7) * 384 + (blockIdx.x >> 3); // XCD swizzle
  const unsigned short* Abase;
  const unsigned short* Wbase;
  const float* bias = nullptr;
  unsigned short* Cu;
  int ldc, bn;
  long long bm;
  if (bid < 1024) {
    const int z = bid >> 8, y = (bid >> 7) & 1, xm = bid & 127;
    Abase = hbf;
    Wbase = preABT_l + (size_t)z * 256 * 128;
    Cu = AB + (size_t)z * NN * 256;
    ldc = 256; bn = y * 128; bm = (long long)xm * 128;
  } else {
    const int idx = bid - 1024;
    const int z = idx >> 9, xm = idx & 511;
    Abase = eaf;
    Wbase = foldT_l + (size_t)z * 128 * 128;
    bias = bfold_l + z * 128;
    Cu = Mb + (size_t)z * EE * 128;
    ldc = 128; bn = 0; bm = (long long)xm * 128;
  }

  const int tid = threadIdx.x;
  const int w = tid >> 6;
  const int lane = tid & 63;
  const int quad = lane >> 4;
  const int c16 = lane & 15;
  const int srow = lane >> 2;
  const int sslot = (lane & 3) << 3;

  f4 acc[2][8];
#pragma unroll
  for (int mt = 0; mt < 2; ++mt)
#pragma unroll
    for (int nt = 0; nt < 8; ++nt) acc[mt][nt] = (f4){0.f, 0.f, 0.f, 0.f};

  const unsigned short* whp = Wbase + (long long)(bn + srow) * 128 + sslot;
  const unsigned short* ahp = Abase + (bm + srow) * 128 + sslot;
  const int swr8 = ((quad ^ ((c16 >> 1) & 3)) << 3);

  auto stage = [&](int bi, int k0) {
#pragma unroll
    for (int ch = w; ch < 8; ch += 4) {
      gll16(ahp + (long long)ch * 16 * 128 + k0, AhS + bi * 4096 + ch * 512);
      gll16(whp + (long long)ch * 16 * 128 + k0, BhS + bi * 4096 + ch * 512);
    }
  };
  auto fragmfma = [&](int bi) {
    hfrag ah[2];
#pragma unroll
    for (int mt = 0; mt < 2; ++mt)
      ah[mt] = *(const hfrag*)&AhS[bi * 4096 + (w * 32 + mt * 16 + c16) * 32 + swr8];
#pragma unroll
    for (int nt = 0; nt < 8; ++nt) {
      hfrag bh = *(const hfrag*)&BhS[bi * 4096 + (nt * 16 + c16) * 32 + swr8];
#pragma unroll
      for (int mt = 0; mt < 2; ++mt)
        acc[mt][nt] = __builtin_amdgcn_mfma_f32_16x16x32_f16(ah[mt], bh, acc[mt][nt], 0, 0, 0);
    }
  };

  stage(0, 0);
  __syncthreads();
#pragma unroll
  for (int kt = 0; kt < 4; ++kt) {
    const int bi = kt & 1;
    if (kt < 3) stage(bi ^ 1, (kt + 1) << 5);
    fragmfma(bi);
    __syncthreads();
  }

  // epilogue phase 1: acc -> LDS [row][colLocal] fp16 (staging LDS is free)
#pragma unroll
  for (int nt = 0; nt < 8; ++nt) {
    const int colL = nt * 16 + c16;
    const float bv = bias ? bias[colL] : 0.f;
#pragma unroll
    for (int mt = 0; mt < 2; ++mt) {
#pragma unroll
      for (int r = 0; r < 4; ++r) {
        const int row = w * 32 + mt * 16 + quad * 4 + r;
        S[row * 128 + colL] = f2h(acc[mt][nt][r] + bv);
      }
    }
  }
  __syncthreads();
  // epilogue phase 2: coalesced 16B stores (each wave writes 1 KB runs)
#pragma unroll
  for (int p = 0; p < 8; ++p) {
    const int row = p * 16 + (tid >> 4);
    const int co = (tid & 15) * 8; // ushort offset, 16B chunk
    *(uint4*)&Cu[(bm + row) * ldc + bn + co] = *(const uint4*)&S[row * 128 + co];
  }
}

// ---------------------------------------------------------------------------
// fp16 MFMA GEMM (templated modes): C[M,Nc] = A[M,K] @ W[K,Nc], fp32 acc.
// A-staging modes (ASRC):
//   1: fp16 ushort input (pre-swizzled), gll copy       [P gemm]
//   3: lin-fused: K=256 two-phase. k<128: A = P_id + s*P_amp + invs*P_att +
//      bpost (ds-write; p0=P fp16, p2=s, p3=invs, p4=bpost). k>=128: A = hbf
//      (Av, gll copy) vs folded Wx@Wlin half of B. Epilogue accumulates BN
//      column stats into p1 (colsum|colsq).
//   4: fp32 / rowcount (p0=cntf) -- global mean pool divide (ds-write)
// OHALF: epilogue stores fp16. NT = column fragments. r1 sync structure.
// ---------------------------------------------------------------------------
template <int ASRC, int NT, bool BIAS, bool RELU, bool OHALF>
__global__ __launch_bounds__(256) void mgemm(
    const void* __restrict__ Av, const unsigned short* __restrict__ WT,
    const float* __restrict__ bias,
    float* __restrict__ C, AuxP aux,
    int Nc, int K, int lda, int ldc,
    long long bsA, long long bsW, long long bsC, int bsBias)
{
  constexpr bool COPYA = (ASRC == 1);
  constexpr int BST = NT * 16 * 32; // ushorts per B buffer

  const int z = blockIdx.z;
  WT += (long long)z * bsW;
  if (BIAS) bias += (long long)z * bsBias;
  float* Cf = C + (OHALF ? 0 : (long long)z * bsC);
  unsigned short* Cu = (unsigned short*)C + (OHALF ? (long long)z * bsC : 0);

  __shared__ __align__(16) unsigned short AhS[2 * 128 * 32];
  __shared__ __align__(16) unsigned short BhS[2 * BST];

  const int tid = threadIdx.x;
  const long long bm = (long long)blockIdx.x * 128;
  const int bn = blockIdx.y * (NT * 16);
  const int w = tid >> 6;
  const int lane = tid & 63;
  const int quad = lane >> 4;
  const int c16 = lane & 15;
  const int srow = lane >> 2;        // staging row within 16-row chunk
  const int sslot = (lane & 3) << 3; // staging slot (ushort offset)

  // ds-write-mode indices: each thread produces 16 A elements of one row-half
  const int arow = tid >> 1;
  const int sel = tid & 1;
  const long long rowsrc = bm + arow;

  f4 acc[2][NT];
#pragma unroll
  for (int mt = 0; mt < 2; ++mt)
#pragma unroll
    for (int nt = 0; nt < NT; ++nt) acc[mt][nt] = (f4){0.f, 0.f, 0.f, 0.f};

  // lane-invariant staging bases
  const unsigned short* whp = WT + (long long)(bn + srow) * K + sslot;

  const unsigned short* ahp = nullptr;
  if (COPYA || ASRC == 3)
    ahp = (const unsigned short*)Av + (long long)z * bsA + (bm + srow) * (long long)lda + sslot;

  // ds-write-mode A state (ASRC 3 / 4)
  float invdc = 1.f;
  float sv = 0.f, iv = 0.f;
  const float* apA = nullptr;
  const unsigned short* Prow_base = nullptr;
  if (ASRC == 3) {
    Prow_base = (const unsigned short*)aux.p0 + rowsrc * 384;
    sv = aux.p2[rowsrc];
    iv = aux.p3[rowsrc];
  } else if (ASRC == 4) {
    apA = (const float*)Av + (long long)z * bsA + rowsrc * lda;
    invdc = 1.f / fmaxf(aux.p0[rowsrc], 1.f);
  }
  // swizzled LDS write offsets for ds-write-mode A
  const int swa = (arow >> 1) & 3;
  const int s0us = arow * 32 + (((2 * sel) ^ swa) << 3);
  const int s1us = arow * 32 + (((2 * sel + 1) ^ swa) << 3);

  // fragment-read swizzle: slot quad ^ ((row>>1)&3); row bits 1..2 == c16 bits
  const int swr8 = ((quad ^ ((c16 >> 1) & 3)) << 3);

  auto stageB = [&](int bi, int k0) {
#pragma unroll
    for (int ch = w; ch < NT; ch += 4)
      gll16(whp + (long long)ch * 16 * K + k0, BhS + bi * BST + ch * 512);
  };
  auto stageA = [&](int bi, int k0) { // gll copy of A rows (k0 relative to lda)
#pragma unroll
    for (int ch = w; ch < 8; ch += 4)
      gll16(ahp + (long long)ch * 16 * lda + k0, AhS + bi * 4096 + ch * 512);
  };
  auto stageLoad = [&](int k0, float* va) {
    const int ck0 = k0 + sel * 16;
    if (ASRC == 3) {
      const unsigned short* Prow = Prow_base + ((ck0 >> 5) * 96) + (ck0 & 31);
      float pid[16], pam[16], pat[16];
      ld8hf(Prow, pid); ld8hf(Prow + 8, pid + 8);
      ld8hf(Prow + 32, pam); ld8hf(Prow + 40, pam + 8);
      ld8hf(Prow + 64, pat); ld8hf(Prow + 72, pat + 8);
#pragma unroll
      for (int i = 0; i < 16; ++i)
        va[i] = pid[i] + sv * pam[i] + iv * pat[i] + aux.p4[ck0 + i];
    } else {
      *(float4*)&va[0] = *(const float4*)(apA + ck0);
      *(float4*)&va[4] = *(const float4*)(apA + ck0 + 4);
      *(float4*)&va[8] = *(const float4*)(apA + ck0 + 8);
      *(float4*)&va[12] = *(const float4*)(apA + ck0 + 12);
    }
  };
  auto stageWrite = [&](int bi, const float* va) {
    hfrag hv0, hv1;
#pragma unroll
    for (int i = 0; i < 16; ++i) {
      float x = va[i];
      if (ASRC == 4) x *= invdc;
      if (i < 8) hv0[i] = (_Float16)x;
      else       hv1[i - 8] = (_Float16)x;
    }
    *(hfrag*)&AhS[bi * 4096 + s0us] = hv0;
    *(hfrag*)&AhS[bi * 4096 + s1us] = hv1;
  };
  auto fragmfma = [&](int bi) {
    hfrag ah[2];
#pragma unroll
    for (int mt = 0; mt < 2; ++mt) {
      const int r = w * 32 + mt * 16 + c16;
      ah[mt] = *(const hfrag*)&AhS[bi * 4096 + r * 32 + swr8];
    }
#pragma unroll
    for (int nt = 0; nt < NT; ++nt) {
      const int r = nt * 16 + c16;
      hfrag bh = *(const hfrag*)&BhS[bi * BST + r * 32 + swr8];
#pragma unroll
      for (int mt = 0; mt < 2; ++mt)
        acc[mt][nt] = __builtin_amdgcn_mfma_f32_16x16x32_f16(ah[mt], bh, acc[mt][nt], 0, 0, 0);
    }
  };

  float va[16];
  const int nk = K >> 5;

  // prologue: fill buffer 0 (ASRC3's tile 0 is ds-mode)
  if (COPYA) {
    stageA(0, 0);
    stageB(0, 0);
  } else {
    stageLoad(0, va);
    stageB(0, 0);
    stageWrite(0, va);
  }
  __syncthreads();

  for (int kt = 0; kt < nk; ++kt) {
    const int bi = kt & 1;
    const bool pf = (kt + 1 < nk);
    bool nextds = false;
    if (pf) {
      const int k0 = (kt + 1) << 5;
      stageB(bi ^ 1, k0);
      if (COPYA) {
        stageA(bi ^ 1, k0);
      } else if (ASRC == 3 && k0 >= 128) {
        stageA(bi ^ 1, k0 - 128); // copy phase: A = hbf (x-through path)
      } else {
        stageLoad(k0, va);
        nextds = true;
      }
    }
    fragmfma(bi);
    if (nextds) stageWrite(bi ^ 1, va);
    __syncthreads();
  }

  // epilogue: C/D layout col=lane&15, row=quad*4+reg
  float ls[NT], lq[NT];
#pragma unroll
  for (int nt = 0; nt < NT; ++nt) { ls[nt] = 0.f; lq[nt] = 0.f; }
#pragma unroll
  for (int nt = 0; nt < NT; ++nt) {
    int col = bn + nt * 16 + c16;
    if (col >= Nc) continue;
    float bv = BIAS ? bias[col] : 0.f;
#pragma unroll
    for (int mt = 0; mt < 2; ++mt) {
#pragma unroll
      for (int r = 0; r < 4; ++r) {
        long long row = bm + w * 32 + mt * 16 + quad * 4 + r;
        float v = acc[mt][nt][r] + bv;
        if (RELU) v = fmaxf(v, 0.f);
        if (ASRC == 3) { ls[nt] += v; lq[nt] += v * v; }
        if (OHALF) Cu[row * ldc + col] = f2h(v);
        else Cf[row * ldc + col] = v;
      }
    }
  }
  if constexpr (ASRC == 3) {
    // fused BN column partial stats: LDS reduce + one global atomic per col
    float* csum = (float*)AhS;  // reuse LDS (all waves past final barrier)
    float* csq = csum + 128;
    if (tid < 128) { csum[tid] = 0.f; csq[tid] = 0.f; }
    __syncthreads();
#pragma unroll
    for (int nt = 0; nt < NT; ++nt) {
      int col = bn + nt * 16 + c16;
      atomicAdd(&csum[col], ls[nt]);
      atomicAdd(&csq[col], lq[nt]);
    }
    __syncthreads();
    float* colsum = (float*)aux.p1;
    if (tid < 128) {
      atomicAdd(&colsum[tid], csum[tid]);
      atomicAdd(&colsum[128 + tid], csq[tid]);
    }
  }
}

// ---------------------------------------------------------------------------
// edge encoder: fp16 DIRECTLY in CSR slot order, PRE-SWIZZLED; 2 edges/block
// ---------------------------------------------------------------------------
__global__ __launch_bounds__(256) void edge_enc(
    const float* __restrict__ eat, const float* __restrict__ We,
    const float* __restrict__ be, const int* __restrict__ slot_of,
    unsigned short* __restrict__ ef)
{
  int e = blockIdx.x * 2 + (threadIdx.x >> 7);
  int c = threadIdx.x & 127;
  float acc = be[c];
#pragma unroll
  for (int k = 0; k < 4; ++k) acc += eat[e * 4 + k] * We[k * 128 + c];
  long long slot = slot_of[e];
  ef[slot * 128 + swk((int)slot, c)] = f2h(fmaxf(acc, 0.f));
}

// ---------------------------------------------------------------------------
// CSR build: count -> scan (also inits cursor + s/invs) -> scatter
// ---------------------------------------------------------------------------
__global__ void count_deg(const int* __restrict__ dst, int* __restrict__ degi)
{
  int e = blockIdx.x * 256 + threadIdx.x;
  if (e < EE) atomicAdd(&degi[dst[e]], 1);
}

__global__ __launch_bounds__(1024) void scan_k(const int* __restrict__ degi,
                                               int* __restrict__ row_off,
                                               int* __restrict__ cursor,
                                               float* __restrict__ s_arr,
                                               float* __restrict__ invs)
{
  __shared__ int tsum[1024];
  int t = threadIdx.x;
  int local[16];
  int base = t * 16;
  int s = 0;
#pragma unroll
  for (int i = 0; i < 16; ++i) { local[i] = s; s += degi[base + i]; }
  tsum[t] = s;
  __syncthreads();
  for (int off = 1; off < 1024; off <<= 1) {
    int v = (t >= off) ? tsum[t - off] : 0;
    __syncthreads();
    tsum[t] += v;
    __syncthreads();
  }
  int prev = (t == 0) ? 0 : tsum[t - 1];
#pragma unroll
  for (int i = 0; i < 16; ++i) {
    int start = prev + local[i];
    row_off[base + i] = start;
    cursor[base + i] = start;
    int cnt = degi[base + i];
    float degc = fmaxf((float)cnt, 1.f);
    float sv = logf(degc + 1.f) / AVG_LOG_F;
    s_arr[base + i] = sv;
    invs[base + i] = 1.f / sv;
  }
  if (t == 1023) row_off[NN] = tsum[1023];
}

__global__ void scatter_k(const int* __restrict__ src, const int* __restrict__ dst,
                          int* __restrict__ cursor,
                          int* __restrict__ slot_of, int* __restrict__ esrc)
{
  int e = blockIdx.x * 256 + threadIdx.x;
  if (e >= EE) return;
  int d = dst[e];
  int slot = atomicAdd(&cursor[d], 1);
  slot_of[e] = slot;
  esrc[slot] = src[e];
}

// ---------------------------------------------------------------------------
// Weight folds (fp32)
// ---------------------------------------------------------------------------
__global__ __launch_bounds__(512) void fold_w(const float* __restrict__ We_conv,
                                              const float* __restrict__ Wpre,
                                              float* __restrict__ Wfold)
{
  int k = blockIdx.x & 127, l = blockIdx.x >> 7;
  int t = threadIdx.x >> 7, f = threadIdx.x & 127;
  const float* wc = We_conv + (long long)(l * 128 + k) * 128;
  const float* wp = Wpre + ((long long)((l * 4 + t) * 384 + 256)) * 128 + f;
  float acc = 0.f;
  for (int j = 0; j < 128; ++j) acc += wc[j] * wp[(long long)j * 128];
  Wfold[((long long)(l * 128 + k)) * 512 + threadIdx.x] = acc;
}

__global__ __launch_bounds__(512) void fold_b(const float* __restrict__ be_conv,
                                              const float* __restrict__ Wpre,
                                              const float* __restrict__ bpre,
                                              float* __restrict__ bfold)
{
  int l = blockIdx.x;
  int t = threadIdx.x >> 7, f = threadIdx.x & 127;
  const float* bc = be_conv + l * 128;
  const float* wp = Wpre + ((long long)((l * 4 + t) * 384 + 256)) * 128 + f;
  float acc = bpre[(l * 4 + t) * 128 + f];
  for (int j = 0; j < 128; ++j) acc += bc[j] * wp[(long long)j * 128];
  bfold[l * 512 + threadIdx.x] = acc;
}

// ---------------------------------------------------------------------------
// pack_all: ALL fp32 -> fp16 swizzled packers + node encoder in ONE launch.
// Segments by blockIdx (128 threads each):
//  [0,3072)      preABT[lt][n(256)][k(128)]
//  [3072,4608)   foldT[lt][n(128)][k(128)]   (reads WfoldF, after fold_w)
//  [4608,6144)   post3T[lt][c(128)][r(512)]  (4 r per thread)
//  [6144,6528)   linT2 lo-half: Wlin transpose [l][n][k<128]
//  [6528,6912)   linT2 hi-half: Wxl[l][o][128+kk] = sum_c Wx[kk][c]*Wlin[c][o]
//  [6912,6976)   w1T[n(64)][k(128)]
//  [6976,23360)  node_enc: hbf[n] = fp16(relu(x@Wa+ba)) swizzled
// ---------------------------------------------------------------------------
__global__ __launch_bounds__(128) void pack_all(
    const float* __restrict__ Wpre, const float* __restrict__ WfoldF,
    const float* __restrict__ Wpost, const float* __restrict__ Wlin,
    const float* __restrict__ W1,
    const float* __restrict__ x, const float* __restrict__ Wa,
    const float* __restrict__ ba,
    unsigned short* __restrict__ preABT, unsigned short* __restrict__ foldT,
    unsigned short* __restrict__ post3T, unsigned short* __restrict__ linT2,
    unsigned short* __restrict__ w1T, unsigned short* __restrict__ hbf)
{
  const int b = blockIdx.x;
  const int t = threadIdx.x;
  if (b < 3072) {                       // preABT
    int lt = b >> 8, n = b & 255, k = t;
    int row = (n < 128) ? k : (128 + k);
    int f = n & 127;
    float v = Wpre[((long long)(lt * 384 + row)) * 128 + f];
    preABT[((long long)(lt * 256 + n)) * 128 + swk(n, k)] = f2h(v);
  } else if (b < 4608) {                // foldT
    int b2 = b - 3072;
    int lt = b2 >> 7, n = b2 & 127, k = t;
    int l = lt >> 2, tw = lt & 3;
    float v = WfoldF[((long long)(l * 128 + k)) * 512 + tw * 128 + n];
    foldT[((long long)(lt * 128 + n)) * 128 + swk(n, k)] = f2h(v);
  } else if (b < 6144) {                // post3T
    int b3 = b - 4608;
    int lt = b3 >> 7, c = b3 & 127;
#pragma unroll
    for (int j = 0; j < 4; ++j) {
      int r = t + 128 * j;
      float v = 0.f;
      if (c < 96)
        v = Wpost[((long long)(lt * 1664 + 128 + (c >> 5) * 512 + r)) * 32 + (c & 31)];
      post3T[((long long)(lt * 128 + c)) * 512 + swk(c, r)] = f2h(v);
    }
  } else if (b < 6528) {                // linT2 low half: Wlin^T
    int b4 = b - 6144;
    int l = b4 >> 7, n = b4 & 127, k = t;
    float v = Wlin[((long long)(l * 128 + k)) * 128 + n];
    linT2[((long long)(l * 128 + n)) * 256 + swk(n, k)] = f2h(v);
  } else if (b < 6912) {                // linT2 high half: Wxl fold
    int b5 = b - 6528;
    int l = b5 >> 7, kk = b5 & 127, o = t;
    float acc = 0.f;
    for (int c = 0; c < 128; ++c) {
      float wx = Wpost[((long long)((l * 4 + (c >> 5)) * 1664 + kk)) * 32 + (c & 31)];
      acc += wx * Wlin[((long long)(l * 128 + c)) * 128 + o];
    }
    linT2[((long long)(l * 128 + o)) * 256 + swk(o, 128 + kk)] = f2h(acc);
  } else if (b < 6976) {                // w1T
    int n = b - 6912, k = t;
    w1T[(long long)n * 128 + swk(n, k)] = f2h(W1[k * 64 + n]);
  } else {                              // node_enc
    int n = b - 6976, c = t;
    float acc = ba[c];
#pragma unroll
    for (int k = 0; k < 11; ++k) acc += x[n * 11 + k] * Wa[k * 128 + c];
    hbf[((long long)n << 7) + swk(n, c)] = f2h(fmaxf(acc, 0.f));
  }
}

// ---------------------------------------------------------------------------
// Per-tower aggregation, ALL FOUR towers in one block, 16B loads.
// Block 256 = 4 nodes x 4 towers x 16 lanes (8 ch each, single us8v load).
// Edges processed in chunks of 4: esrc batch-loaded first, then 8 independent
// 16B loads in flight (breaks the esrc->ABs dependent-latency chain).
// AB and Mb slabs fp16. Accumulation order per channel identical to scalar.
// Output aggs fp16 [N][512], PRE-SWIZZLED (swk) for gll staging by the P gemm.
// ---------------------------------------------------------------------------
__global__ __launch_bounds__(256) void aggregate_ct(
    const unsigned short* __restrict__ ABb, const unsigned short* __restrict__ Mb,
    const int* __restrict__ row_off, const int* __restrict__ esrc,
    unsigned short* __restrict__ aggs)
{
  const int tid = threadIdx.x;
  const int c8 = (tid & 15) << 3;     // 8 channels per lane
  const int z = (tid >> 4) & 3;       // tower
  const int n = blockIdx.x * 4 + (tid >> 6);
  const unsigned short* M = Mb + (long long)z * EE * 128;
  const unsigned short* ABs = ABb + (long long)z * NN * 256;
  unsigned short* ag = aggs + (long long)z * NN * 512;
  const int beg = row_off[n], end = row_off[n + 1];
  const int cnt = end - beg;
  const float degc = fmaxf((float)cnt, 1.0f);
  float aval[8];
  ld8hf(&ABs[(long long)n * 256 + c8], aval);

  float sum[8], sq[8], mn[8], mx[8];
#pragma unroll
  for (int j = 0; j < 8; ++j) {
    sum[j] = 0.f; sq[j] = 0.f; mn[j] = INFINITY; mx[j] = -INFINITY;
  }

  auto upd = [&](const float* mv, const float* bv) {
#pragma unroll
    for (int j = 0; j < 8; ++j) {
      float m = aval[j] + bv[j] + mv[j];
      sum[j] += m; sq[j] += m * m;
      mn[j] = fminf(mn[j], m); mx[j] = fmaxf(mx[j], m);
    }
  };

  for (int s0 = beg; s0 < end; s0 += 4) {
    const int e1 = min(s0 + 1, end - 1);
    const int e2 = min(s0 + 2, end - 1);
    const int e3 = min(s0 + 3, end - 1);
    const int sA = esrc[s0], sB = esrc[e1], sC = esrc[e2], sD = esrc[e3];
    float mA[8], mB[8], mC[8], mD[8], bA[8], bB[8], bC[8], bD[8];
    ld8hf(&M[(long long)s0 * 128 + c8], mA);
    ld8hf(&M[(long long)e1 * 128 + c8], mB);
    ld8hf(&M[(long long)e2 * 128 + c8], mC);
    ld8hf(&M[(long long)e3 * 128 + c8], mD);
    ld8hf(&ABs[(long long)sA * 256 + 128 + c8], bA);
    ld8hf(&ABs[(long long)sB * 256 + 128 + c8], bB);
    ld8hf(&ABs[(long long)sC * 256 + 128 + c8], bC);
    ld8hf(&ABs[(long long)sD * 256 + 128 + c8], bD);
    upd(mA, bA);
    if (s0 + 1 < end) upd(mB, bB);
    if (s0 + 2 < end) upd(mC, bC);
    if (s0 + 3 < end) upd(mD, bD);
  }

  const float inv = 1.0f / degc;
  us8v omean, omin, omax, ostd;
#pragma unroll
  for (int j = 0; j < 8; ++j) {
    float mean = sum[j] * inv;
    float var = sq[j] * inv - mean * mean;
    float stdv = sqrtf(fmaxf(var, 0.f) + 1e-5f);
    float mnv = (cnt > 0) ? mn[j] : 0.f;
    float mxv = (cnt > 0) ? mx[j] : 0.f;
    omean[j] = f2h(mean);
    omin[j] = f2h(mnv);
    omax[j] = f2h(mxv);
    ostd[j] = f2h(stdv);
  }
  const int sc = swk(n, c8);
  const long long base = (long long)n * 512 + sc;
  *(us8v*)&ag[base] = omean;
  *(us8v*)&ag[base + 128] = omin;
  *(us8v*)&ag[base + 256] = omax;
  *(us8v*)&ag[base + 384] = ostd;
}

// ---------------------------------------------------------------------------
// BN apply (coef computed inline from colstats)
// hb = fp16(relu(hn*scale + shift)) pre-swizzled; hn is fp16
// ---------------------------------------------------------------------------
__global__ __launch_bounds__(256) void bn_apply(const unsigned short* __restrict__ hn,
                                                const float* __restrict__ cs,
                                                const float* __restrict__ g,
                                                const float* __restrict__ b,
                                                unsigned short* __restrict__ hb)
{
  int idx = blockIdx.x * 256 + threadIdx.x; // n*128+c
  int c = idx & 127, n = idx >> 7;
  float mean = cs[c] * (1.f / 16384.f);
  float var = cs[128 + c] * (1.f / 16384.f) - mean * mean;
  float sc = g[c] * rsqrtf(var + 1e-5f);
  float v = fmaxf(h2f(hn[idx]) * sc + (b[c] - mean * sc), 0.f);
  hb[((long long)n << 7) + swk(n, c)] = f2h(v);
}

// ---------------------------------------------------------------------------
// Global mean pool (BN+ReLU fused) + head
// ---------------------------------------------------------------------------
__global__ void pool_add(const unsigned short* __restrict__ y, const float* __restrict__ cs,
                         const float* __restrict__ g, const float* __restrict__ b,
                         const int* __restrict__ batch,
                         float* __restrict__ pooled, float* __restrict__ cntf)
{
  int n = blockIdx.x, c = threadIdx.x;
  float mean = cs[c] * (1.f / 16384.f);
  float var = cs[128 + c] * (1.f / 16384.f) - mean * mean;
  float v = fmaxf((h2f(y[(long long)n * 128 + c]) - mean) * rsqrtf(var + 1e-5f) * g[c] + b[c], 0.f);
  int bb = batch[n];
  atomicAdd(&pooled[(long long)bb * 128 + c], v);
  if (c == 0) atomicAdd(&cntf[bb], 1.f);
}

__global__ __launch_bounds__(256) void zstats(const float* __restrict__ z,
                                              float* __restrict__ zm, float* __restrict__ zv)
{
  int j = blockIdx.x; // 64 cols
  float s = 0.f, q = 0.f;
  for (int g = threadIdx.x; g < GG; g += 256) {
    float v = z[g * 64 + j];
    s += v;
    q += v * v;
  }
  __shared__ float ps[256], pq[256];
  ps[threadIdx.x] = s;
  pq[threadIdx.x] = q;
  __syncthreads();
  for (int st = 128; st > 0; st >>= 1) {
    if (threadIdx.x < st) {
      ps[threadIdx.x] += ps[threadIdx.x + st];
      pq[threadIdx.x] += pq[threadIdx.x + st];
    }
    __syncthreads();
  }
  if (threadIdx.x == 0) {
    float m = ps[0] / (float)GG;
    zm[j] = m;
    zv[j] = pq[0] / (float)GG - m * m;
  }
}

__global__ void final_out(const float* __restrict__ z, const float* __restrict__ zm,
                          const float* __restrict__ zv, const float* __restrict__ hg,
                          const float* __restrict__ hb, const float* __restrict__ W2,
                          const float* __restrict__ b2, float* __restrict__ out)
{
  int g = blockIdx.x;
  int j = threadIdx.x; // 64 = one wave
  float v = (z[g * 64 + j] - zm[j]) * rsqrtf(zv[j] + 1e-5f) * hg[j] + hb[j];
  float t = v * W2[j];
#pragma unroll
  for (int off = 32; off > 0; off >>= 1) t += __shfl_down(t, off);
  if (j == 0) out[g] = t + b2[0];
}

// ---------------------------------------------------------------------------
extern "C" void kernel_launch(void* const* d_in, const int* in_sizes, int n_in,
                              void* d_out, int out_size, void* d_ws, size_t ws_size,
                              hipStream_t stream)
{
  (void)in_sizes; (void)n_in; (void)out_size;
  const float* x = (const float*)d_in[0];
  const float* eat = (const float*)d_in[1];
  const int* ei = (const int*)d_in[2];
  const int* batch = (const int*)d_in[3];
  const float* Wa = (const float*)d_in[4];
  const float* ba = (const float*)d_in[5];
  const float* We = (const float*)d_in[6];
  const float* be = (const float*)d_in[7];
  const float* We_conv = (const float*)d_in[8];
  const float* be_conv = (const float*)d_in[9];
  const float* Wpre = (const float*)d_in[10];
  const float* bpre = (const float*)d_in[11];
  const float* Wpost = (const float*)d_in[12];
  const float* bpost = (const float*)d_in[13];
  const float* Wlin = (const float*)d_in[14];
  const float* blin = (const float*)d_in[15];
  const float* bng = (const float*)d_in[16];
  const float* bnb = (const float*)d_in[17];
  const float* W1 = (const float*)d_in[18];
  const float* b1 = (const float*)d_in[19];
  const float* hg = (const float*)d_in[20];
  const float* hb = (const float*)d_in[21];
  const float* W2 = (const float*)d_in[22];
  const float* b2 = (const float*)d_in[23];
  float* out = (float*)d_out;

  const int* srcI = ei;
  const int* dstI = ei + EE;

  char* ws = (char*)d_ws;
  size_t off = 0;
  auto alloc = [&](size_t bytes) -> char* {
    char* p = ws + off;
    off += (bytes + 255) & ~(size_t)255;
    return p;
  };

  unsigned short* hbf = (unsigned short*)alloc((size_t)NN * 128 * 2); // fp16 h
  unsigned short* hn = (unsigned short*)alloc((size_t)NN * 128 * 2);  // fp16 hn
  unsigned short* eaf = (unsigned short*)alloc((size_t)EE * 128 * 2); // fp16 ea, CSR order
  unsigned short* AB = (unsigned short*)alloc((size_t)4 * NN * 256 * 2); // fp16 [T][N][256]
  char* Mregion = alloc((size_t)4 * EE * 128 * 2);           // Mb fp16 [4][E][128]; later P fp16
  unsigned short* Mb = (unsigned short*)Mregion;
  unsigned short* P = (unsigned short*)Mregion;               // fp16 [N][384]
  unsigned short* aggt = (unsigned short*)alloc((size_t)4 * NN * 512 * 2); // fp16 [T][N][512]
  float* s_arr = (float*)alloc((size_t)NN * 4);
  float* invs = (float*)alloc((size_t)NN * 4);
  int* degi = (int*)alloc((size_t)NN * 4);
  int* cursor = (int*)alloc((size_t)NN * 4);
  int* row_off = (int*)alloc((size_t)(NN + 1) * 4);
  int* slot_of = (int*)alloc((size_t)EE * 4);
  int* esrc = (int*)alloc((size_t)EE * 4);
  float* WfoldF = (float*)alloc((size_t)3 * 128 * 512 * 4);
  float* bfold = (float*)alloc((size_t)3 * 512 * 4);
  unsigned short* preABT = (unsigned short*)alloc((size_t)12 * 256 * 128 * 2);
  unsigned short* foldT = (unsigned short*)alloc((size_t)12 * 128 * 128 * 2);
  unsigned short* post3T = (unsigned short*)alloc((size_t)12 * 128 * 512 * 2);
  unsigned short* linT2 = (unsigned short*)alloc((size_t)3 * 128 * 256 * 2); // [Wlin^T | Wx@Wlin]
  unsigned short* w1T = (unsigned short*)alloc((size_t)64 * 128 * 2);
  float* colstats = (float*)alloc(3 * 256 * 4); // one 256-buffer per layer
  float* pooled = (float*)alloc((size_t)GG * 128 * 4);
  float* cntf = (float*)alloc((size_t)GG * 4);
  float* zbuf = (float*)alloc((size_t)GG * 64 * 4);
  float* zm = (float*)alloc(64 * 4);
  float* zv = (float*)alloc(64 * 4);

  if (off > ws_size) return; // bail rather than corrupt

  // ---- graph structure ----
  hipMemsetAsync(degi, 0, (size_t)NN * 4, stream);
  hipMemsetAsync(colstats, 0, 3 * 256 * 4, stream);
  count_deg<<<EE / 256, 256, 0, stream>>>(dstI, degi);
  scan_k<<<1, 1024, 0, stream>>>(degi, row_off, cursor, s_arr, invs);
  scatter_k<<<EE / 256, 256, 0, stream>>>(srcI, dstI, cursor, slot_of, esrc);

  // ---- encoders + weight folds/packing ----
  edge_enc<<<EE / 2, 256, 0, stream>>>(eat, We, be, slot_of, eaf); // after scatter_k
  fold_w<<<384, 512, 0, stream>>>(We_conv, Wpre, WfoldF);
  fold_b<<<3, 512, 0, stream>>>(be_conv, Wpre, bpre, bfold);
  pack_all<<<6976 + NN, 128, 0, stream>>>(Wpre, WfoldF, Wpost, Wlin, W1, x, Wa, ba,
                                          preABT, foldT, post3T, linT2, w1T, hbf);

  for (int l = 0; l < 3; ++l) {
    float* cs_l = colstats + l * 256;
    // merged AB (z=4, both col-halves) + C (z=4) gemms, one dispatch
    abc_gemm<<<3072, 256, 0, stream>>>(
        hbf, preABT + (size_t)l * 4 * 256 * 128, AB,
        eaf, foldT + (size_t)l * 4 * 128 * 128, bfold + l * 512, Mb);
    // stats over m = (A + B[src]) + C ; 4 nodes x 4 towers per block
    aggregate_ct<<<dim3(NN / 4, 1, 1), 256, 0, stream>>>(AB, Mb, row_off, esrc, aggt);
    // P all towers: fp16 [N,512] @ [512,96] (z=4, exact 96-col tile) -> fp16 P
    mgemm<1, 6, false, false, true><<<dim3(NN / 128, 1, 4), 256, 0, stream>>>(
        aggt, post3T + (size_t)l * 4 * 128 * 512, nullptr, (float*)P, AuxP{},
        96, 512, 512, 384, (long long)NN * 512, (long long)128 * 512, 96, 0);
    // lin (K=256 two-phase: P-combine | hbf x-through vs folded Wx@Wlin),
    // + blin; epilogue fuses BN column stats into cs_l; output fp16 hn
    mgemm<3, 8, true, false, true><<<dim3(NN / 128, 1, 1), 256, 0, stream>>>(
        hbf, linT2 + (size_t)l * 128 * 256, blin + l * 128, (float*)hn,
        AuxP{(const float*)P, cs_l, s_arr, invs, bpost + l * 128},
        128, 256, 128, 128, 0, 0, 0, 0);
    if (l < 2)
      bn_apply<<<NN * 128 / 256, 256, 0, stream>>>(hn, cs_l, bng + l * 128,
                                                   bnb + l * 128, hbf);
  }

  // ---- pooling (BN+ReLU fused) + head ----
  hipMemsetAsync(pooled, 0, (size_t)GG * 128 * 4, stream);
  hipMemsetAsync(cntf, 0, (size_t)GG * 4, stream);
  pool_add<<<NN, 128, 0, stream>>>(hn, colstats + 2 * 256,
                                   bng + 2 * 128, bnb + 2 * 128, batch, pooled, cntf);
  mgemm<4, 4, true, true, false><<<dim3(GG / 128, 1, 1), 256, 0, stream>>>(
      pooled, w1T, b1, zbuf, AuxP{cntf, nullptr, nullptr, nullptr, nullptr},
      64, 128, 128, 64, 0, 0, 0, 0);
  zstats<<<64, 256, 0, stream>>>(zbuf, zm, zv);
  final_out<<<GG, 64, 0, stream>>>(zbuf, zm, zv, hg, hb, W2, b2, out);
}

// Round 14
// 544.639 us; speedup vs baseline: 1.2311x; 1.0275x over previous
//
#include <hip/hip_runtime.h>
#include <hip/hip_bf16.h>

#define DEVFN static __device__ __forceinline__

constexpr int NN = 16384;
constexpr int EE = 65536;
constexpr int GG = 512;
constexpr float AVG_LOG_F = 1.0227308671603782f; // (sum d*log d, d=1..4, hist 1,2,3,4)/10

typedef _Float16 hfrag __attribute__((ext_vector_type(8))); // 8 fp16 = 4 VGPR (MFMA A/B)
typedef __attribute__((ext_vector_type(4))) float f4;       // MFMA C/D
typedef __attribute__((ext_vector_type(8))) unsigned short us8v; // 16B fp16 vector

// fp32 <-> fp16 (RNE, native v_cvt). Measured (r5-r8): bf16 slabs +0.0097
// absmax; fp16 slabs noise-level. All intermediates + GEMM operands fp16.
DEVFN unsigned short f2h(float f) {
  _Float16 h = (_Float16)f;
  unsigned short r; __builtin_memcpy(&r, &h, 2); return r;
}
DEVFN float h2f(unsigned short s) {
  _Float16 h; __builtin_memcpy(&h, &s, 2); return (float)h;
}

// load 8 fp16 (single 16B) -> float[8]
DEVFN void ld8hf(const unsigned short* p, float* o) {
  us8v v = *(const us8v*)p;
#pragma unroll
  for (int i = 0; i < 8; ++i) o[i] = h2f(v[i]);
}

// XOR swizzle for packed fp16 [R][K] operand arrays staged with global_load_lds:
// element (row,k) lives at row*K + swk(row,k). Within each 32-wide K window the
// four 8-element slots are permuted by (row>>1)&3 so a wave's ds_read_b128
// fragment reads become a permutation of a contiguous 1 KB region ->
// bank-conflict-free. global_load_lds copies LINEARLY, so the swizzle is baked
// into the packed global layout (both-sides rule, #21).
DEVFN int swk(int row, int k) {
  return (k & ~31) + ((((k >> 3) & 3) ^ ((row >> 1) & 3)) << 3) + (k & 7);
}

// async global->LDS, 16 B per lane; LDS dest = wave-uniform base + lane*16
DEVFN void gll16(const unsigned short* g, unsigned short* l) {
  __builtin_amdgcn_global_load_lds(
      (__attribute__((address_space(1))) void*)g,
      (__attribute__((address_space(3))) void*)l, 16, 0, 0);
}

// aux pointer bundle for fused A-staging modes
struct AuxP {
  const float* p0;
  const float* p1;
  const float* p2;
  const float* p3;
  const float* p4;
};

// ---------------------------------------------------------------------------
// Merged AB + C GEMM (one dispatch per layer; both are copy-mode K=128 NT=8).
//  bid < 1024 : AB role. A = hbf [N,128]; W = preABT tower z; out fp16
//               AB[z][N][256]. (z=bid>>8, y=(bid>>7)&1, xm=bid&127)
//  bid >= 1024: C role.  A = eaf [E,128] (CSR order); W = foldT tower z;
//               out fp16 Mb[z][E][128], bias=bfold. (z=idx>>9, xm=idx&511)
// r1 sync structure; coalesced LDS-repack epilogue. Repack uses an XOR col
// swizzle (col ^ ((row>>2&7)<<4)): r13 PMC showed the unswizzled repack's
// phase-1 stores were a 4-way bank conflict (1.57M cycles/dispatch) -- four
// quads write rows {0,4,8,12}+r at the same column, row*128 us == bank 0.
// The XOR spreads the 4 quads across banks; chunk-constant within 8-ushort
// reads so phase-2 16B loads stay contiguous. (XCD swizzle reverted: r13
// measured it neutral-to-negative -- no inter-block panel reuse here.)
// ---------------------------------------------------------------------------
__global__ __launch_bounds__(256) void abc_gemm(
    const unsigned short* __restrict__ hbf, const unsigned short* __restrict__ preABT_l,
    unsigned short* __restrict__ AB,
    const unsigned short* __restrict__ eaf, const unsigned short* __restrict__ foldT_l,
    const float* __restrict__ bfold_l, unsigned short* __restrict__ Mb)
{
  __shared__ __align__(16) unsigned short S[16384]; // 32 KB staging; epilogue repack
  unsigned short* AhS = S;
  unsigned short* BhS = S + 8192;

  const int bid = blockIdx.x;
  const unsigned short* Abase;
  const unsigned short* Wbase;
  const float* bias = nullptr;
  unsigned short* Cu;
  int ldc, bn;
  long long bm;
  if (bid < 1024) {
    const int z = bid >> 8, y = (bid >> 7) & 1, xm = bid & 127;
    Abase = hbf;
    Wbase = preABT_l + (size_t)z * 256 * 128;
    Cu = AB + (size_t)z * NN * 256;
    ldc = 256; bn = y * 128; bm = (long long)xm * 128;
  } else {
    const int idx = bid - 1024;
    const int z = idx >> 9, xm = idx & 511;
    Abase = eaf;
    Wbase = foldT_l + (size_t)z * 128 * 128;
    bias = bfold_l + z * 128;
    Cu = Mb + (size_t)z * EE * 128;
    ldc = 128; bn = 0; bm = (long long)xm * 128;
  }

  const int tid = threadIdx.x;
  const int w = tid >> 6;
  const int lane = tid & 63;
  const int quad = lane >> 4;
  const int c16 = lane & 15;
  const int srow = lane >> 2;
  const int sslot = (lane & 3) << 3;

  f4 acc[2][8];
#pragma unroll
  for (int mt = 0; mt < 2; ++mt)
#pragma unroll
    for (int nt = 0; nt < 8; ++nt) acc[mt][nt] = (f4){0.f, 0.f, 0.f, 0.f};

  const unsigned short* whp = Wbase + (long long)(bn + srow) * 128 + sslot;
  const unsigned short* ahp = Abase + (bm + srow) * 128 + sslot;
  const int swr8 = ((quad ^ ((c16 >> 1) & 3)) << 3);

  auto stage = [&](int bi, int k0) {
#pragma unroll
    for (int ch = w; ch < 8; ch += 4) {
      gll16(ahp + (long long)ch * 16 * 128 + k0, AhS + bi * 4096 + ch * 512);
      gll16(whp + (long long)ch * 16 * 128 + k0, BhS + bi * 4096 + ch * 512);
    }
  };
  auto fragmfma = [&](int bi) {
    hfrag ah[2];
#pragma unroll
    for (int mt = 0; mt < 2; ++mt)
      ah[mt] = *(const hfrag*)&AhS[bi * 4096 + (w * 32 + mt * 16 + c16) * 32 + swr8];
#pragma unroll
    for (int nt = 0; nt < 8; ++nt) {
      hfrag bh = *(const hfrag*)&BhS[bi * 4096 + (nt * 16 + c16) * 32 + swr8];
#pragma unroll
      for (int mt = 0; mt < 2; ++mt)
        acc[mt][nt] = __builtin_amdgcn_mfma_f32_16x16x32_f16(ah[mt], bh, acc[mt][nt], 0, 0, 0);
    }
  };

  stage(0, 0);
  __syncthreads();
#pragma unroll
  for (int kt = 0; kt < 4; ++kt) {
    const int bi = kt & 1;
    if (kt < 3) stage(bi ^ 1, (kt + 1) << 5);
    fragmfma(bi);
    __syncthreads();
  }

  // epilogue phase 1: acc -> LDS [row][col ^ xorv(row)] fp16 (bank-conflict-
  // free: 4 quads' xorv = {0,16,32,48} us -> stores cover all 32 banks)
#pragma unroll
  for (int nt = 0; nt < 8; ++nt) {
    const int colL = nt * 16 + c16;
    const float bv = bias ? bias[colL] : 0.f;
#pragma unroll
    for (int mt = 0; mt < 2; ++mt) {
#pragma unroll
      for (int r = 0; r < 4; ++r) {
        const int row = w * 32 + mt * 16 + quad * 4 + r;
        const int xv = ((row >> 2) & 7) << 4;
        S[row * 128 + (colL ^ xv)] = f2h(acc[mt][nt][r] + bv);
      }
    }
  }
  __syncthreads();
  // epilogue phase 2: coalesced 16B stores (chunk-constant XOR -> contiguous)
#pragma unroll
  for (int p = 0; p < 8; ++p) {
    const int row = p * 16 + (tid >> 4);
    const int xv = ((row >> 2) & 7) << 4;
    const int co = (tid & 15) * 8; // ushort offset, 16B chunk
    *(uint4*)&Cu[(bm + row) * ldc + bn + co] = *(const uint4*)&S[row * 128 + (co ^ xv)];
  }
}

// ---------------------------------------------------------------------------
// fp16 MFMA GEMM (templated modes): C[M,Nc] = A[M,K] @ W[K,Nc], fp32 acc.
// A-staging modes (ASRC):
//   1: fp16 ushort input (pre-swizzled), gll copy       [P gemm]
//   3: lin-fused: K=256 two-phase. k<128: A = P_id + s*P_amp + invs*P_att +
//      bpost (ds-write; p0=P fp16, p2=s, p3=invs, p4=bpost). k>=128: A = hbf
//      (Av, gll copy) vs folded Wx@Wlin half of B. Epilogue accumulates BN
//      column stats into p1 (colsum|colsq).
//   4: fp32 / rowcount (p0=cntf) -- global mean pool divide (ds-write)
// OHALF: epilogue stores fp16. NT = column fragments. r1 sync structure.
// ---------------------------------------------------------------------------
template <int ASRC, int NT, bool BIAS, bool RELU, bool OHALF>
__global__ __launch_bounds__(256) void mgemm(
    const void* __restrict__ Av, const unsigned short* __restrict__ WT,
    const float* __restrict__ bias,
    float* __restrict__ C, AuxP aux,
    int Nc, int K, int lda, int ldc,
    long long bsA, long long bsW, long long bsC, int bsBias)
{
  constexpr bool COPYA = (ASRC == 1);
  constexpr int BST = NT * 16 * 32; // ushorts per B buffer

  const int z = blockIdx.z;
  WT += (long long)z * bsW;
  if (BIAS) bias += (long long)z * bsBias;
  float* Cf = C + (OHALF ? 0 : (long long)z * bsC);
  unsigned short* Cu = (unsigned short*)C + (OHALF ? (long long)z * bsC : 0);

  __shared__ __align__(16) unsigned short AhS[2 * 128 * 32];
  __shared__ __align__(16) unsigned short BhS[2 * BST];

  const int tid = threadIdx.x;
  const long long bm = (long long)blockIdx.x * 128;
  const int bn = blockIdx.y * (NT * 16);
  const int w = tid >> 6;
  const int lane = tid & 63;
  const int quad = lane >> 4;
  const int c16 = lane & 15;
  const int srow = lane >> 2;        // staging row within 16-row chunk
  const int sslot = (lane & 3) << 3; // staging slot (ushort offset)

  // ds-write-mode indices: each thread produces 16 A elements of one row-half
  const int arow = tid >> 1;
  const int sel = tid & 1;
  const long long rowsrc = bm + arow;

  f4 acc[2][NT];
#pragma unroll
  for (int mt = 0; mt < 2; ++mt)
#pragma unroll
    for (int nt = 0; nt < NT; ++nt) acc[mt][nt] = (f4){0.f, 0.f, 0.f, 0.f};

  // lane-invariant staging bases
  const unsigned short* whp = WT + (long long)(bn + srow) * K + sslot;

  const unsigned short* ahp = nullptr;
  if (COPYA || ASRC == 3)
    ahp = (const unsigned short*)Av + (long long)z * bsA + (bm + srow) * (long long)lda + sslot;

  // ds-write-mode A state (ASRC 3 / 4)
  float invdc = 1.f;
  float sv = 0.f, iv = 0.f;
  const float* apA = nullptr;
  const unsigned short* Prow_base = nullptr;
  if (ASRC == 3) {
    Prow_base = (const unsigned short*)aux.p0 + rowsrc * 384;
    sv = aux.p2[rowsrc];
    iv = aux.p3[rowsrc];
  } else if (ASRC == 4) {
    apA = (const float*)Av + (long long)z * bsA + rowsrc * lda;
    invdc = 1.f / fmaxf(aux.p0[rowsrc], 1.f);
  }
  // swizzled LDS write offsets for ds-write-mode A
  const int swa = (arow >> 1) & 3;
  const int s0us = arow * 32 + (((2 * sel) ^ swa) << 3);
  const int s1us = arow * 32 + (((2 * sel + 1) ^ swa) << 3);

  // fragment-read swizzle: slot quad ^ ((row>>1)&3); row bits 1..2 == c16 bits
  const int swr8 = ((quad ^ ((c16 >> 1) & 3)) << 3);

  auto stageB = [&](int bi, int k0) {
#pragma unroll
    for (int ch = w; ch < NT; ch += 4)
      gll16(whp + (long long)ch * 16 * K + k0, BhS + bi * BST + ch * 512);
  };
  auto stageA = [&](int bi, int k0) { // gll copy of A rows (k0 relative to lda)
#pragma unroll
    for (int ch = w; ch < 8; ch += 4)
      gll16(ahp + (long long)ch * 16 * lda + k0, AhS + bi * 4096 + ch * 512);
  };
  auto stageLoad = [&](int k0, float* va) {
    const int ck0 = k0 + sel * 16;
    if (ASRC == 3) {
      const unsigned short* Prow = Prow_base + ((ck0 >> 5) * 96) + (ck0 & 31);
      float pid[16], pam[16], pat[16];
      ld8hf(Prow, pid); ld8hf(Prow + 8, pid + 8);
      ld8hf(Prow + 32, pam); ld8hf(Prow + 40, pam + 8);
      ld8hf(Prow + 64, pat); ld8hf(Prow + 72, pat + 8);
#pragma unroll
      for (int i = 0; i < 16; ++i)
        va[i] = pid[i] + sv * pam[i] + iv * pat[i] + aux.p4[ck0 + i];
    } else {
      *(float4*)&va[0] = *(const float4*)(apA + ck0);
      *(float4*)&va[4] = *(const float4*)(apA + ck0 + 4);
      *(float4*)&va[8] = *(const float4*)(apA + ck0 + 8);
      *(float4*)&va[12] = *(const float4*)(apA + ck0 + 12);
    }
  };
  auto stageWrite = [&](int bi, const float* va) {
    hfrag hv0, hv1;
#pragma unroll
    for (int i = 0; i < 16; ++i) {
      float x = va[i];
      if (ASRC == 4) x *= invdc;
      if (i < 8) hv0[i] = (_Float16)x;
      else       hv1[i - 8] = (_Float16)x;
    }
    *(hfrag*)&AhS[bi * 4096 + s0us] = hv0;
    *(hfrag*)&AhS[bi * 4096 + s1us] = hv1;
  };
  auto fragmfma = [&](int bi) {
    hfrag ah[2];
#pragma unroll
    for (int mt = 0; mt < 2; ++mt) {
      const int r = w * 32 + mt * 16 + c16;
      ah[mt] = *(const hfrag*)&AhS[bi * 4096 + r * 32 + swr8];
    }
#pragma unroll
    for (int nt = 0; nt < NT; ++nt) {
      const int r = nt * 16 + c16;
      hfrag bh = *(const hfrag*)&BhS[bi * BST + r * 32 + swr8];
#pragma unroll
      for (int mt = 0; mt < 2; ++mt)
        acc[mt][nt] = __builtin_amdgcn_mfma_f32_16x16x32_f16(ah[mt], bh, acc[mt][nt], 0, 0, 0);
    }
  };

  float va[16];
  const int nk = K >> 5;

  // prologue: fill buffer 0 (ASRC3's tile 0 is ds-mode)
  if (COPYA) {
    stageA(0, 0);
    stageB(0, 0);
  } else {
    stageLoad(0, va);
    stageB(0, 0);
    stageWrite(0, va);
  }
  __syncthreads();

  for (int kt = 0; kt < nk; ++kt) {
    const int bi = kt & 1;
    const bool pf = (kt + 1 < nk);
    bool nextds = false;
    if (pf) {
      const int k0 = (kt + 1) << 5;
      stageB(bi ^ 1, k0);
      if (COPYA) {
        stageA(bi ^ 1, k0);
      } else if (ASRC == 3 && k0 >= 128) {
        stageA(bi ^ 1, k0 - 128); // copy phase: A = hbf (x-through path)
      } else {
        stageLoad(k0, va);
        nextds = true;
      }
    }
    fragmfma(bi);
    if (nextds) stageWrite(bi ^ 1, va);
    __syncthreads();
  }

  // epilogue: C/D layout col=lane&15, row=quad*4+reg
  float ls[NT], lq[NT];
#pragma unroll
  for (int nt = 0; nt < NT; ++nt) { ls[nt] = 0.f; lq[nt] = 0.f; }
#pragma unroll
  for (int nt = 0; nt < NT; ++nt) {
    int col = bn + nt * 16 + c16;
    if (col >= Nc) continue;
    float bv = BIAS ? bias[col] : 0.f;
#pragma unroll
    for (int mt = 0; mt < 2; ++mt) {
#pragma unroll
      for (int r = 0; r < 4; ++r) {
        long long row = bm + w * 32 + mt * 16 + quad * 4 + r;
        float v = acc[mt][nt][r] + bv;
        if (RELU) v = fmaxf(v, 0.f);
        if (ASRC == 3) { ls[nt] += v; lq[nt] += v * v; }
        if (OHALF) Cu[row * ldc + col] = f2h(v);
        else Cf[row * ldc + col] = v;
      }
    }
  }
  if constexpr (ASRC == 3) {
    // fused BN column partial stats: LDS reduce + one global atomic per col
    float* csum = (float*)AhS;  // reuse LDS (all waves past final barrier)
    float* csq = csum + 128;
    if (tid < 128) { csum[tid] = 0.f; csq[tid] = 0.f; }
    __syncthreads();
#pragma unroll
    for (int nt = 0; nt < NT; ++nt) {
      int col = bn + nt * 16 + c16;
      atomicAdd(&csum[col], ls[nt]);
      atomicAdd(&csq[col], lq[nt]);
    }
    __syncthreads();
    float* colsum = (float*)aux.p1;
    if (tid < 128) {
      atomicAdd(&colsum[tid], csum[tid]);
      atomicAdd(&colsum[128 + tid], csq[tid]);
    }
  }
}

// ---------------------------------------------------------------------------
// edge encoder: fp16 DIRECTLY in CSR slot order, PRE-SWIZZLED; 2 edges/block
// ---------------------------------------------------------------------------
__global__ __launch_bounds__(256) void edge_enc(
    const float* __restrict__ eat, const float* __restrict__ We,
    const float* __restrict__ be, const int* __restrict__ slot_of,
    unsigned short* __restrict__ ef)
{
  int e = blockIdx.x * 2 + (threadIdx.x >> 7);
  int c = threadIdx.x & 127;
  float acc = be[c];
#pragma unroll
  for (int k = 0; k < 4; ++k) acc += eat[e * 4 + k] * We[k * 128 + c];
  long long slot = slot_of[e];
  ef[slot * 128 + swk((int)slot, c)] = f2h(fmaxf(acc, 0.f));
}

// ---------------------------------------------------------------------------
// CSR build: count -> scan (also inits cursor + s/invs) -> scatter
// ---------------------------------------------------------------------------
__global__ void count_deg(const int* __restrict__ dst, int* __restrict__ degi)
{
  int e = blockIdx.x * 256 + threadIdx.x;
  if (e < EE) atomicAdd(&degi[dst[e]], 1);
}

__global__ __launch_bounds__(1024) void scan_k(const int* __restrict__ degi,
                                               int* __restrict__ row_off,
                                               int* __restrict__ cursor,
                                               float* __restrict__ s_arr,
                                               float* __restrict__ invs)
{
  __shared__ int tsum[1024];
  int t = threadIdx.x;
  int local[16];
  int base = t * 16;
  int s = 0;
#pragma unroll
  for (int i = 0; i < 16; ++i) { local[i] = s; s += degi[base + i]; }
  tsum[t] = s;
  __syncthreads();
  for (int off = 1; off < 1024; off <<= 1) {
    int v = (t >= off) ? tsum[t - off] : 0;
    __syncthreads();
    tsum[t] += v;
    __syncthreads();
  }
  int prev = (t == 0) ? 0 : tsum[t - 1];
#pragma unroll
  for (int i = 0; i < 16; ++i) {
    int start = prev + local[i];
    row_off[base + i] = start;
    cursor[base + i] = start;
    int cnt = degi[base + i];
    float degc = fmaxf((float)cnt, 1.f);
    float sv = logf(degc + 1.f) / AVG_LOG_F;
    s_arr[base + i] = sv;
    invs[base + i] = 1.f / sv;
  }
  if (t == 1023) row_off[NN] = tsum[1023];
}

__global__ void scatter_k(const int* __restrict__ src, const int* __restrict__ dst,
                          int* __restrict__ cursor,
                          int* __restrict__ slot_of, int* __restrict__ esrc)
{
  int e = blockIdx.x * 256 + threadIdx.x;
  if (e >= EE) return;
  int d = dst[e];
  int slot = atomicAdd(&cursor[d], 1);
  slot_of[e] = slot;
  esrc[slot] = src[e];
}

// ---------------------------------------------------------------------------
// Weight folds (fp32)
// ---------------------------------------------------------------------------
__global__ __launch_bounds__(512) void fold_w(const float* __restrict__ We_conv,
                                              const float* __restrict__ Wpre,
                                              float* __restrict__ Wfold)
{
  int k = blockIdx.x & 127, l = blockIdx.x >> 7;
  int t = threadIdx.x >> 7, f = threadIdx.x & 127;
  const float* wc = We_conv + (long long)(l * 128 + k) * 128;
  const float* wp = Wpre + ((long long)((l * 4 + t) * 384 + 256)) * 128 + f;
  float acc = 0.f;
  for (int j = 0; j < 128; ++j) acc += wc[j] * wp[(long long)j * 128];
  Wfold[((long long)(l * 128 + k)) * 512 + threadIdx.x] = acc;
}

__global__ __launch_bounds__(512) void fold_b(const float* __restrict__ be_conv,
                                              const float* __restrict__ Wpre,
                                              const float* __restrict__ bpre,
                                              float* __restrict__ bfold)
{
  int l = blockIdx.x;
  int t = threadIdx.x >> 7, f = threadIdx.x & 127;
  const float* bc = be_conv + l * 128;
  const float* wp = Wpre + ((long long)((l * 4 + t) * 384 + 256)) * 128 + f;
  float acc = bpre[(l * 4 + t) * 128 + f];
  for (int j = 0; j < 128; ++j) acc += bc[j] * wp[(long long)j * 128];
  bfold[l * 512 + threadIdx.x] = acc;
}

// ---------------------------------------------------------------------------
// pack_all: ALL fp32 -> fp16 swizzled packers + node encoder in ONE launch.
// Segments by blockIdx (128 threads each):
//  [0,3072)      preABT[lt][n(256)][k(128)]
//  [3072,4608)   foldT[lt][n(128)][k(128)]   (reads WfoldF, after fold_w)
//  [4608,6144)   post3T[lt][c(128)][r(512)]  (4 r per thread)
//  [6144,6528)   linT2 lo-half: Wlin transpose [l][n][k<128]
//  [6528,6912)   linT2 hi-half: Wxl[l][o][128+kk] = sum_c Wx[kk][c]*Wlin[c][o]
//  [6912,6976)   w1T[n(64)][k(128)]
//  [6976,23360)  node_enc: hbf[n] = fp16(relu(x@Wa+ba)) swizzled
// ---------------------------------------------------------------------------
__global__ __launch_bounds__(128) void pack_all(
    const float* __restrict__ Wpre, const float* __restrict__ WfoldF,
    const float* __restrict__ Wpost, const float* __restrict__ Wlin,
    const float* __restrict__ W1,
    const float* __restrict__ x, const float* __restrict__ Wa,
    const float* __restrict__ ba,
    unsigned short* __restrict__ preABT, unsigned short* __restrict__ foldT,
    unsigned short* __restrict__ post3T, unsigned short* __restrict__ linT2,
    unsigned short* __restrict__ w1T, unsigned short* __restrict__ hbf)
{
  const int b = blockIdx.x;
  const int t = threadIdx.x;
  if (b < 3072) {                       // preABT
    int lt = b >> 8, n = b & 255, k = t;
    int row = (n < 128) ? k : (128 + k);
    int f = n & 127;
    float v = Wpre[((long long)(lt * 384 + row)) * 128 + f];
    preABT[((long long)(lt * 256 + n)) * 128 + swk(n, k)] = f2h(v);
  } else if (b < 4608) {                // foldT
    int b2 = b - 3072;
    int lt = b2 >> 7, n = b2 & 127, k = t;
    int l = lt >> 2, tw = lt & 3;
    float v = WfoldF[((long long)(l * 128 + k)) * 512 + tw * 128 + n];
    foldT[((long long)(lt * 128 + n)) * 128 + swk(n, k)] = f2h(v);
  } else if (b < 6144) {                // post3T
    int b3 = b - 4608;
    int lt = b3 >> 7, c = b3 & 127;
#pragma unroll
    for (int j = 0; j < 4; ++j) {
      int r = t + 128 * j;
      float v = 0.f;
      if (c < 96)
        v = Wpost[((long long)(lt * 1664 + 128 + (c >> 5) * 512 + r)) * 32 + (c & 31)];
      post3T[((long long)(lt * 128 + c)) * 512 + swk(c, r)] = f2h(v);
    }
  } else if (b < 6528) {                // linT2 low half: Wlin^T
    int b4 = b - 6144;
    int l = b4 >> 7, n = b4 & 127, k = t;
    float v = Wlin[((long long)(l * 128 + k)) * 128 + n];
    linT2[((long long)(l * 128 + n)) * 256 + swk(n, k)] = f2h(v);
  } else if (b < 6912) {                // linT2 high half: Wxl fold
    int b5 = b - 6528;
    int l = b5 >> 7, kk = b5 & 127, o = t;
    float acc = 0.f;
    for (int c = 0; c < 128; ++c) {
      float wx = Wpost[((long long)((l * 4 + (c >> 5)) * 1664 + kk)) * 32 + (c & 31)];
      acc += wx * Wlin[((long long)(l * 128 + c)) * 128 + o];
    }
    linT2[((long long)(l * 128 + o)) * 256 + swk(o, 128 + kk)] = f2h(acc);
  } else if (b < 6976) {                // w1T
    int n = b - 6912, k = t;
    w1T[(long long)n * 128 + swk(n, k)] = f2h(W1[k * 64 + n]);
  } else {                              // node_enc
    int n = b - 6976, c = t;
    float acc = ba[c];
#pragma unroll
    for (int k = 0; k < 11; ++k) acc += x[n * 11 + k] * Wa[k * 128 + c];
    hbf[((long long)n << 7) + swk(n, c)] = f2h(fmaxf(acc, 0.f));
  }
}

// ---------------------------------------------------------------------------
// Per-tower aggregation, ALL FOUR towers in one block, 16B loads.
// Block 256 = 4 nodes x 4 towers x 16 lanes (8 ch each, single us8v load).
// Edges processed in chunks of 4: esrc batch-loaded first, then 8 independent
// 16B loads in flight (breaks the esrc->ABs dependent-latency chain).
// AB and Mb slabs fp16. Accumulation order per channel identical to scalar.
// Output aggs fp16 [N][512], PRE-SWIZZLED (swk) for gll staging by the P gemm.
// ---------------------------------------------------------------------------
__global__ __launch_bounds__(256) void aggregate_ct(
    const unsigned short* __restrict__ ABb, const unsigned short* __restrict__ Mb,
    const int* __restrict__ row_off, const int* __restrict__ esrc,
    unsigned short* __restrict__ aggs)
{
  const int tid = threadIdx.x;
  const int c8 = (tid & 15) << 3;     // 8 channels per lane
  const int z = (tid >> 4) & 3;       // tower
  const int n = blockIdx.x * 4 + (tid >> 6);
  const unsigned short* M = Mb + (long long)z * EE * 128;
  const unsigned short* ABs = ABb + (long long)z * NN * 256;
  unsigned short* ag = aggs + (long long)z * NN * 512;
  const int beg = row_off[n], end = row_off[n + 1];
  const int cnt = end - beg;
  const float degc = fmaxf((float)cnt, 1.0f);
  float aval[8];
  ld8hf(&ABs[(long long)n * 256 + c8], aval);

  float sum[8], sq[8], mn[8], mx[8];
#pragma unroll
  for (int j = 0; j < 8; ++j) {
    sum[j] = 0.f; sq[j] = 0.f; mn[j] = INFINITY; mx[j] = -INFINITY;
  }

  auto upd = [&](const float* mv, const float* bv) {
#pragma unroll
    for (int j = 0; j < 8; ++j) {
      float m = aval[j] + bv[j] + mv[j];
      sum[j] += m; sq[j] += m * m;
      mn[j] = fminf(mn[j], m); mx[j] = fmaxf(mx[j], m);
    }
  };

  for (int s0 = beg; s0 < end; s0 += 4) {
    const int e1 = min(s0 + 1, end - 1);
    const int e2 = min(s0 + 2, end - 1);
    const int e3 = min(s0 + 3, end - 1);
    const int sA = esrc[s0], sB = esrc[e1], sC = esrc[e2], sD = esrc[e3];
    float mA[8], mB[8], mC[8], mD[8], bA[8], bB[8], bC[8], bD[8];
    ld8hf(&M[(long long)s0 * 128 + c8], mA);
    ld8hf(&M[(long long)e1 * 128 + c8], mB);
    ld8hf(&M[(long long)e2 * 128 + c8], mC);
    ld8hf(&M[(long long)e3 * 128 + c8], mD);
    ld8hf(&ABs[(long long)sA * 256 + 128 + c8], bA);
    ld8hf(&ABs[(long long)sB * 256 + 128 + c8], bB);
    ld8hf(&ABs[(long long)sC * 256 + 128 + c8], bC);
    ld8hf(&ABs[(long long)sD * 256 + 128 + c8], bD);
    upd(mA, bA);
    if (s0 + 1 < end) upd(mB, bB);
    if (s0 + 2 < end) upd(mC, bC);
    if (s0 + 3 < end) upd(mD, bD);
  }

  const float inv = 1.0f / degc;
  us8v omean, omin, omax, ostd;
#pragma unroll
  for (int j = 0; j < 8; ++j) {
    float mean = sum[j] * inv;
    float var = sq[j] * inv - mean * mean;
    float stdv = sqrtf(fmaxf(var, 0.f) + 1e-5f);
    float mnv = (cnt > 0) ? mn[j] : 0.f;
    float mxv = (cnt > 0) ? mx[j] : 0.f;
    omean[j] = f2h(mean);
    omin[j] = f2h(mnv);
    omax[j] = f2h(mxv);
    ostd[j] = f2h(stdv);
  }
  const int sc = swk(n, c8);
  const long long base = (long long)n * 512 + sc;
  *(us8v*)&ag[base] = omean;
  *(us8v*)&ag[base + 128] = omin;
  *(us8v*)&ag[base + 256] = omax;
  *(us8v*)&ag[base + 384] = ostd;
}

// ---------------------------------------------------------------------------
// BN apply (coef computed inline from colstats)
// hb = fp16(relu(hn*scale + shift)) pre-swizzled; hn is fp16
// ---------------------------------------------------------------------------
__global__ __launch_bounds__(256) void bn_apply(const unsigned short* __restrict__ hn,
                                                const float* __restrict__ cs,
                                                const float* __restrict__ g,
                                                const float* __restrict__ b,
                                                unsigned short* __restrict__ hb)
{
  int idx = blockIdx.x * 256 + threadIdx.x; // n*128+c
  int c = idx & 127, n = idx >> 7;
  float mean = cs[c] * (1.f / 16384.f);
  float var = cs[128 + c] * (1.f / 16384.f) - mean * mean;
  float sc = g[c] * rsqrtf(var + 1e-5f);
  float v = fmaxf(h2f(hn[idx]) * sc + (b[c] - mean * sc), 0.f);
  hb[((long long)n << 7) + swk(n, c)] = f2h(v);
}

// ---------------------------------------------------------------------------
// Global mean pool (BN+ReLU fused) + head
// ---------------------------------------------------------------------------
__global__ void pool_add(const unsigned short* __restrict__ y, const float* __restrict__ cs,
                         const float* __restrict__ g, const float* __restrict__ b,
                         const int* __restrict__ batch,
                         float* __restrict__ pooled, float* __restrict__ cntf)
{
  int n = blockIdx.x, c = threadIdx.x;
  float mean = cs[c] * (1.f / 16384.f);
  float var = cs[128 + c] * (1.f / 16384.f) - mean * mean;
  float v = fmaxf((h2f(y[(long long)n * 128 + c]) - mean) * rsqrtf(var + 1e-5f) * g[c] + b[c], 0.f);
  int bb = batch[n];
  atomicAdd(&pooled[(long long)bb * 128 + c], v);
  if (c == 0) atomicAdd(&cntf[bb], 1.f);
}

__global__ __launch_bounds__(256) void zstats(const float* __restrict__ z,
                                              float* __restrict__ zm, float* __restrict__ zv)
{
  int j = blockIdx.x; // 64 cols
  float s = 0.f, q = 0.f;
  for (int g = threadIdx.x; g < GG; g += 256) {
    float v = z[g * 64 + j];
    s += v;
    q += v * v;
  }
  __shared__ float ps[256], pq[256];
  ps[threadIdx.x] = s;
  pq[threadIdx.x] = q;
  __syncthreads();
  for (int st = 128; st > 0; st >>= 1) {
    if (threadIdx.x < st) {
      ps[threadIdx.x] += ps[threadIdx.x + st];
      pq[threadIdx.x] += pq[threadIdx.x + st];
    }
    __syncthreads();
  }
  if (threadIdx.x == 0) {
    float m = ps[0] / (float)GG;
    zm[j] = m;
    zv[j] = pq[0] / (float)GG - m * m;
  }
}

__global__ void final_out(const float* __restrict__ z, const float* __restrict__ zm,
                          const float* __restrict__ zv, const float* __restrict__ hg,
                          const float* __restrict__ hb, const float* __restrict__ W2,
                          const float* __restrict__ b2, float* __restrict__ out)
{
  int g = blockIdx.x;
  int j = threadIdx.x; // 64 = one wave
  float v = (z[g * 64 + j] - zm[j]) * rsqrtf(zv[j] + 1e-5f) * hg[j] + hb[j];
  float t = v * W2[j];
#pragma unroll
  for (int off = 32; off > 0; off >>= 1) t += __shfl_down(t, off);
  if (j == 0) out[g] = t + b2[0];
}

// ---------------------------------------------------------------------------
extern "C" void kernel_launch(void* const* d_in, const int* in_sizes, int n_in,
                              void* d_out, int out_size, void* d_ws, size_t ws_size,
                              hipStream_t stream)
{
  (void)in_sizes; (void)n_in; (void)out_size;
  const float* x = (const float*)d_in[0];
  const float* eat = (const float*)d_in[1];
  const int* ei = (const int*)d_in[2];
  const int* batch = (const int*)d_in[3];
  const float* Wa = (const float*)d_in[4];
  const float* ba = (const float*)d_in[5];
  const float* We = (const float*)d_in[6];
  const float* be = (const float*)d_in[7];
  const float* We_conv = (const float*)d_in[8];
  const float* be_conv = (const float*)d_in[9];
  const float* Wpre = (const float*)d_in[10];
  const float* bpre = (const float*)d_in[11];
  const float* Wpost = (const float*)d_in[12];
  const float* bpost = (const float*)d_in[13];
  const float* Wlin = (const float*)d_in[14];
  const float* blin = (const float*)d_in[15];
  const float* bng = (const float*)d_in[16];
  const float* bnb = (const float*)d_in[17];
  const float* W1 = (const float*)d_in[18];
  const float* b1 = (const float*)d_in[19];
  const float* hg = (const float*)d_in[20];
  const float* hb = (const float*)d_in[21];
  const float* W2 = (const float*)d_in[22];
  const float* b2 = (const float*)d_in[23];
  float* out = (float*)d_out;

  const int* srcI = ei;
  const int* dstI = ei + EE;

  char* ws = (char*)d_ws;
  size_t off = 0;
  auto alloc = [&](size_t bytes) -> char* {
    char* p = ws + off;
    off += (bytes + 255) & ~(size_t)255;
    return p;
  };

  unsigned short* hbf = (unsigned short*)alloc((size_t)NN * 128 * 2); // fp16 h
  unsigned short* hn = (unsigned short*)alloc((size_t)NN * 128 * 2);  // fp16 hn
  unsigned short* eaf = (unsigned short*)alloc((size_t)EE * 128 * 2); // fp16 ea, CSR order
  unsigned short* AB = (unsigned short*)alloc((size_t)4 * NN * 256 * 2); // fp16 [T][N][256]
  char* Mregion = alloc((size_t)4 * EE * 128 * 2);           // Mb fp16 [4][E][128]; later P fp16
  unsigned short* Mb = (unsigned short*)Mregion;
  unsigned short* P = (unsigned short*)Mregion;               // fp16 [N][384]
  unsigned short* aggt = (unsigned short*)alloc((size_t)4 * NN * 512 * 2); // fp16 [T][N][512]
  float* s_arr = (float*)alloc((size_t)NN * 4);
  float* invs = (float*)alloc((size_t)NN * 4);
  int* degi = (int*)alloc((size_t)NN * 4);
  int* cursor = (int*)alloc((size_t)NN * 4);
  int* row_off = (int*)alloc((size_t)(NN + 1) * 4);
  int* slot_of = (int*)alloc((size_t)EE * 4);
  int* esrc = (int*)alloc((size_t)EE * 4);
  float* WfoldF = (float*)alloc((size_t)3 * 128 * 512 * 4);
  float* bfold = (float*)alloc((size_t)3 * 512 * 4);
  unsigned short* preABT = (unsigned short*)alloc((size_t)12 * 256 * 128 * 2);
  unsigned short* foldT = (unsigned short*)alloc((size_t)12 * 128 * 128 * 2);
  unsigned short* post3T = (unsigned short*)alloc((size_t)12 * 128 * 512 * 2);
  unsigned short* linT2 = (unsigned short*)alloc((size_t)3 * 128 * 256 * 2); // [Wlin^T | Wx@Wlin]
  unsigned short* w1T = (unsigned short*)alloc((size_t)64 * 128 * 2);
  float* colstats = (float*)alloc(3 * 256 * 4); // one 256-buffer per layer
  float* pooled = (float*)alloc((size_t)GG * 128 * 4);
  float* cntf = (float*)alloc((size_t)GG * 4);
  float* zbuf = (float*)alloc((size_t)GG * 64 * 4);
  float* zm = (float*)alloc(64 * 4);
  float* zv = (float*)alloc(64 * 4);

  if (off > ws_size) return; // bail rather than corrupt

  // ---- graph structure ----
  hipMemsetAsync(degi, 0, (size_t)NN * 4, stream);
  hipMemsetAsync(colstats, 0, 3 * 256 * 4, stream);
  count_deg<<<EE / 256, 256, 0, stream>>>(dstI, degi);
  scan_k<<<1, 1024, 0, stream>>>(degi, row_off, cursor, s_arr, invs);
  scatter_k<<<EE / 256, 256, 0, stream>>>(srcI, dstI, cursor, slot_of, esrc);

  // ---- encoders + weight folds/packing ----
  edge_enc<<<EE / 2, 256, 0, stream>>>(eat, We, be, slot_of, eaf); // after scatter_k
  fold_w<<<384, 512, 0, stream>>>(We_conv, Wpre, WfoldF);
  fold_b<<<3, 512, 0, stream>>>(be_conv, Wpre, bpre, bfold);
  pack_all<<<6976 + NN, 128, 0, stream>>>(Wpre, WfoldF, Wpost, Wlin, W1, x, Wa, ba,
                                          preABT, foldT, post3T, linT2, w1T, hbf);

  for (int l = 0; l < 3; ++l) {
    float* cs_l = colstats + l * 256;
    // merged AB (z=4, both col-halves) + C (z=4) gemms, one dispatch
    abc_gemm<<<3072, 256, 0, stream>>>(
        hbf, preABT + (size_t)l * 4 * 256 * 128, AB,
        eaf, foldT + (size_t)l * 4 * 128 * 128, bfold + l * 512, Mb);
    // stats over m = (A + B[src]) + C ; 4 nodes x 4 towers per block
    aggregate_ct<<<dim3(NN / 4, 1, 1), 256, 0, stream>>>(AB, Mb, row_off, esrc, aggt);
    // P all towers: fp16 [N,512] @ [512,96] (z=4, exact 96-col tile) -> fp16 P
    mgemm<1, 6, false, false, true><<<dim3(NN / 128, 1, 4), 256, 0, stream>>>(
        aggt, post3T + (size_t)l * 4 * 128 * 512, nullptr, (float*)P, AuxP{},
        96, 512, 512, 384, (long long)NN * 512, (long long)128 * 512, 96, 0);
    // lin (K=256 two-phase: P-combine | hbf x-through vs folded Wx@Wlin),
    // + blin; epilogue fuses BN column stats into cs_l; output fp16 hn
    mgemm<3, 8, true, false, true><<<dim3(NN / 128, 1, 1), 256, 0, stream>>>(
        hbf, linT2 + (size_t)l * 128 * 256, blin + l * 128, (float*)hn,
        AuxP{(const float*)P, cs_l, s_arr, invs, bpost + l * 128},
        128, 256, 128, 128, 0, 0, 0, 0);
    if (l < 2)
      bn_apply<<<NN * 128 / 256, 256, 0, stream>>>(hn, cs_l, bng + l * 128,
                                                   bnb + l * 128, hbf);
  }

  // ---- pooling (BN+ReLU fused) + head ----
  hipMemsetAsync(pooled, 0, (size_t)GG * 128 * 4, stream);
  hipMemsetAsync(cntf, 0, (size_t)GG * 4, stream);
  pool_add<<<NN, 128, 0, stream>>>(hn, colstats + 2 * 256,
                                   bng + 2 * 128, bnb + 2 * 128, batch, pooled, cntf);
  mgemm<4, 4, true, true, false><<<dim3(GG / 128, 1, 1), 256, 0, stream>>>(
      pooled, w1T, b1, zbuf, AuxP{cntf, nullptr, nullptr, nullptr, nullptr},
      64, 128, 128, 64, 0, 0, 0, 0);
  zstats<<<64, 256, 0, stream>>>(zbuf, zm, zv);
  final_out<<<GG, 64, 0, stream>>>(zbuf, zm, zv, hg, hb, W2, b2, out);
}